// Round 11
// baseline (410.764 us; speedup 1.0000x reference)
//
#include <hip/hip_runtime.h>
#include <hip/hip_bf16.h>
#include <stdint.h>

#define NN 50000
#define NE 800000
#define IND 128
#define HID 256
#define MPAD 50048      // 782 * 64
#define NBLK 49         // ceil(NN/1024)

// atomic-free CSR build geometry
#define NCH 64          // edge chunks
#define CHSZ 12500      // NE / NCH
#define NRG 8           // dst ranges
#define RGSZ 6250       // NN / NRG (25 KB LDS histogram)

typedef unsigned int uint32;
typedef unsigned short ushort_t;
typedef __attribute__((ext_vector_type(8))) short short8;
typedef __attribute__((ext_vector_type(4))) float f32x4;

typedef const __attribute__((address_space(1))) void* gptr_t;
typedef __attribute__((address_space(3))) void* lptr_t;

__device__ __forceinline__ ushort_t f2b(float f) {
  uint32 u = __float_as_uint(f);
  u = (u + 0x7fffu + ((u >> 16) & 1u)) >> 16;
  return (ushort_t)u;
}
__device__ __forceinline__ float blo(uint32 u) { return __uint_as_float(u << 16); }
__device__ __forceinline__ float bhi(uint32 u) { return __uint_as_float(u & 0xffff0000u); }
__device__ __forceinline__ uint32 pack2(float a, float b) {
  return (uint32)f2b(a) | ((uint32)f2b(b) << 16);
}

// fragment-packed weight layout: 16B chunk per (colgrp wid, kstep ks, frag j, lane),
// lane = ((k&31)>>3)*16 + (col&15). One coalesced 1KB load per B-fragment.
__device__ __forceinline__ int packidx(int col, int k, int Kd) {
  int lane = ((k & 31) >> 3) * 16 + (col & 15);
  int c = (((col >> 6) * (Kd >> 5) + (k >> 5)) * 4 + ((col >> 4) & 3)) * 64 + lane;
  return c * 8 + (k & 7);
}

// ---------------- CSR build (no global atomics, no rnk array) ----------------
__global__ __launch_bounds__(256) void histp_k(const int* __restrict__ dst,
                                               uint32* __restrict__ partial) {
  __shared__ uint32 lh[RGSZ];
  const int c = blockIdx.x & (NCH - 1);
  const int rg = blockIdx.x >> 6;
  const int r0 = rg * RGSZ;
  for (int i = threadIdx.x; i < RGSZ; i += 256) lh[i] = 0;
  __syncthreads();
  const int e0 = c * CHSZ;
  for (int i = threadIdx.x; i < CHSZ; i += 256) {
    int d = dst[e0 + i] - r0;
    if ((unsigned)d < (unsigned)RGSZ) atomicAdd(&lh[d], 1u);
  }
  __syncthreads();
  uint32* po = partial + (size_t)c * NN + r0;
  for (int i = threadIdx.x; i < RGSZ; i += 256) po[i] = lh[i];
}

__global__ void coff_k(uint32* __restrict__ partial, int* __restrict__ cnt) {
  int bin = blockIdx.x * 256 + threadIdx.x;
  if (bin >= NN) return;
  uint32 run = 0;
#pragma unroll
  for (int c = 0; c < NCH; c++) {
    uint32 t = partial[(size_t)c * NN + bin];
    partial[(size_t)c * NN + bin] = run;
    run += t;
  }
  cnt[bin] = (int)run;
}

__global__ void bsum_k(const int* __restrict__ cnt, int* __restrict__ bsum) {
  __shared__ int ws[16];
  const int tid = threadIdx.x, ln = tid & 63, wv = tid >> 6;
  int i = blockIdx.x * 1024 + tid;
  int v = (i < NN) ? cnt[i] : 0;
#pragma unroll
  for (int d = 32; d; d >>= 1) v += __shfl_down(v, d, 64);
  if (ln == 0) ws[wv] = v;
  __syncthreads();
  if (tid < 16) {
    int s = ws[tid];
#pragma unroll
    for (int d = 8; d; d >>= 1) s += __shfl_down(s, d, 64);
    if (tid == 0) bsum[blockIdx.x] = s;
  }
}

__global__ void bscan_k(int* __restrict__ bsum, int* __restrict__ rp) {
  int tid = threadIdx.x;
  int v = (tid < NBLK) ? bsum[tid] : 0;
  int x = v;
#pragma unroll
  for (int d = 1; d < 64; d <<= 1) {
    int t = __shfl_up(x, d, 64);
    if (tid >= d) x += t;
  }
  if (tid < NBLK) bsum[tid] = x - v;
  if (tid == 0) rp[NN] = NE;
}

__global__ void scan2_k(const int* __restrict__ cnt, const int* __restrict__ bsum,
                        int* __restrict__ rp) {
  __shared__ int ws[16];
  const int tid = threadIdx.x, ln = tid & 63, wv = tid >> 6;
  int i = blockIdx.x * 1024 + tid;
  int v = (i < NN) ? cnt[i] : 0;
  int x = v;
#pragma unroll
  for (int d = 1; d < 64; d <<= 1) {
    int t = __shfl_up(x, d, 64);
    if (ln >= d) x += t;
  }
  if (ln == 63) ws[wv] = x;
  __syncthreads();
  if (tid < 16) {
    int s = ws[tid];
#pragma unroll
    for (int d = 1; d < 16; d <<= 1) {
      int t = __shfl_up(s, d, 64);
      if (tid >= d) s += t;
    }
    ws[tid] = s;
  }
  __syncthreads();
  int excl = x - v + (wv ? ws[wv - 1] : 0) + bsum[blockIdx.x];
  if (i < NN) rp[i] = excl;
}

__global__ __launch_bounds__(256) void scat3_k(const int* __restrict__ src,
                                               const int* __restrict__ dst,
                                               const int* __restrict__ rp,
                                               const uint32* __restrict__ partial,
                                               int* __restrict__ esrc) {
  __shared__ int base[RGSZ];     // 25 KB
  __shared__ uint32 lh[RGSZ];    // 25 KB
  const int c = blockIdx.x & (NCH - 1);
  const int rg = blockIdx.x >> 6;
  const int r0 = rg * RGSZ;
  const uint32* po = partial + (size_t)c * NN + r0;
  const int* rpo = rp + r0;
  for (int i = threadIdx.x; i < RGSZ; i += 256) {
    base[i] = rpo[i] + (int)po[i];
    lh[i] = 0;
  }
  __syncthreads();
  const int e0 = c * CHSZ;
  for (int i = threadIdx.x; i < CHSZ; i += 256) {
    int e = e0 + i;
    int d = dst[e] - r0;
    if ((unsigned)d < (unsigned)RGSZ) {
      int r = (int)atomicAdd(&lh[d], 1u);
      esrc[base[d] + r] = src[e];
    }
  }
}

// ---------------- prep: weights (6 transposes -> frag-pack) + BN folding ----------------
__global__ void prep_k(const float* __restrict__ w1_0, const float* __restrict__ w2_0,
                       const float* __restrict__ w1_r, const float* __restrict__ w2_r,
                       const float* b1_0, const float* b2_0, const float* g0,
                       const float* be0, const float* m0, const float* v0,
                       const float* b1_r, const float* b2_r, const float* g_r,
                       const float* be_r, const float* m_r, const float* v_r,
                       ushort_t* __restrict__ wt,
                       float* bi1, float* sc2, float* bi2) {
  const int which = blockIdx.y;
  if (which < 6) {
    const int n = blockIdx.x, k = threadIdx.x;
    const float* w; ushort_t* o; int K = HID;
    switch (which) {
      case 0: w = w1_0; o = wt; K = IND; break;
      case 1: w = w2_0; o = wt + HID * IND; break;
      case 2: w = w1_r; o = wt + HID * IND + 1 * HID * HID; break;
      case 3: w = w2_r; o = wt + HID * IND + 2 * HID * HID; break;
      case 4: w = w1_r + HID * HID; o = wt + HID * IND + 3 * HID * HID; break;
      default: w = w2_r + HID * HID; o = wt + HID * IND + 4 * HID * HID; break;
    }
    if (k < K) o[packidx(n, k, K)] = f2b(w[(size_t)k * HID + n]);
  } else {
    const int l = blockIdx.x;
    if (l >= 3) return;
    const int j = threadIdx.x;
    float b1, b2, g, be, m, v;
    if (l == 0) { b1 = b1_0[j]; b2 = b2_0[j]; g = g0[j]; be = be0[j]; m = m0[j]; v = v0[j]; }
    else { int o = (l - 1) * HID + j; b1 = b1_r[o]; b2 = b2_r[o]; g = g_r[o]; be = be_r[o]; m = m_r[o]; v = v_r[o]; }
    int o = l * HID + j;
    bi1[o] = b1;
    float s = g * rsqrtf(v + 1e-5f);
    sc2[o] = s;
    bi2[o] = (b2 - m) * s + be;
  }
}

// cast x (NN x 128 fp32) -> bf16
__global__ void x2b_k(const float* __restrict__ x, ushort_t* __restrict__ xb) {
  int i = blockIdx.x * 256 + threadIdx.x;
  const int n = NN * IND / 2;
  if (i < n) {
    float2 f = ((const float2*)x)[i];
    ((uint32*)xb)[i] = pack2(f.x, f.y);
  }
}

// ---------------- aggregation: z = h + sum h_j ----------------
// R11: 16-deep gather batches (2x outstanding loads/wave vs R10's 8) + idx
// prefetch + single branch-free padded-16 tail (clamped dup idx = L1-hit,
// 0/1 fma weights). Mean deg 16 -> most nodes are one full batch + one tail.
__global__ void agg256_k(const ushort_t* __restrict__ h, const int* __restrict__ rp,
                         const int* __restrict__ esrc, ushort_t* __restrict__ z) {
  int wid = threadIdx.x >> 6, lane = threadIdx.x & 63;
  int node = blockIdx.x * 4 + wid;
  if (node >= NN) return;
  const uint2* hp = (const uint2*)h;
  uint2 v = hp[(size_t)node * 64 + lane];
  float a0 = blo(v.x), a1 = bhi(v.x), a2 = blo(v.y), a3 = bhi(v.y);
  int e0 = rp[node], e1 = rp[node + 1];
  const int n16 = (e1 - e0) >> 4;
  int s[16], sn[16];
  if (n16 > 0) {
#pragma unroll
    for (int q = 0; q < 16; q++) s[q] = esrc[e0 + q];
  }
  for (int b = 0; b < n16; b++) {
    const int e = e0 + b * 16;
    if (b + 1 < n16) {
#pragma unroll
      for (int q = 0; q < 16; q++) sn[q] = esrc[e + 16 + q];
    }
    uint2 u[16];
#pragma unroll
    for (int q = 0; q < 16; q++) u[q] = hp[(size_t)s[q] * 64 + lane];
#pragma unroll
    for (int q = 0; q < 16; q++) {
      a0 += blo(u[q].x); a1 += bhi(u[q].x); a2 += blo(u[q].y); a3 += bhi(u[q].y);
    }
#pragma unroll
    for (int q = 0; q < 16; q++) s[q] = sn[q];
  }
  const int e = e0 + n16 * 16;
  if (e < e1) {
    const int last = e1 - 1;
    int idx[16]; float w[16];
#pragma unroll
    for (int q = 0; q < 16; q++) {
      int ee = e + q;
      w[q] = (ee < e1) ? 1.f : 0.f;
      idx[q] = esrc[(ee < e1) ? ee : last];
    }
    uint2 u[16];
#pragma unroll
    for (int q = 0; q < 16; q++) u[q] = hp[(size_t)idx[q] * 64 + lane];
#pragma unroll
    for (int q = 0; q < 16; q++) {
      a0 = fmaf(w[q], blo(u[q].x), a0);
      a1 = fmaf(w[q], bhi(u[q].x), a1);
      a2 = fmaf(w[q], blo(u[q].y), a2);
      a3 = fmaf(w[q], bhi(u[q].y), a3);
    }
  }
  uint2 o; o.x = pack2(a0, a1); o.y = pack2(a2, a3);
  ((uint2*)z)[(size_t)node * 64 + lane] = o;
}

__global__ void agg128_k(const ushort_t* __restrict__ h, const int* __restrict__ rp,
                         const int* __restrict__ esrc, ushort_t* __restrict__ z) {
  int wid = threadIdx.x >> 6, lane = threadIdx.x & 63;
  int node = blockIdx.x * 4 + wid;
  if (node >= NN) return;
  const uint32* hp = (const uint32*)h;
  uint32 v = hp[(size_t)node * 64 + lane];
  float a0 = blo(v), a1 = bhi(v);
  int e0 = rp[node], e1 = rp[node + 1];
  const int n16 = (e1 - e0) >> 4;
  int s[16], sn[16];
  if (n16 > 0) {
#pragma unroll
    for (int q = 0; q < 16; q++) s[q] = esrc[e0 + q];
  }
  for (int b = 0; b < n16; b++) {
    const int e = e0 + b * 16;
    if (b + 1 < n16) {
#pragma unroll
      for (int q = 0; q < 16; q++) sn[q] = esrc[e + 16 + q];
    }
    uint32 u[16];
#pragma unroll
    for (int q = 0; q < 16; q++) u[q] = hp[(size_t)s[q] * 64 + lane];
#pragma unroll
    for (int q = 0; q < 16; q++) { a0 += blo(u[q]); a1 += bhi(u[q]); }
#pragma unroll
    for (int q = 0; q < 16; q++) s[q] = sn[q];
  }
  const int e = e0 + n16 * 16;
  if (e < e1) {
    const int last = e1 - 1;
    int idx[16]; float w[16];
#pragma unroll
    for (int q = 0; q < 16; q++) {
      int ee = e + q;
      w[q] = (ee < e1) ? 1.f : 0.f;
      idx[q] = esrc[(ee < e1) ? ee : last];
    }
    uint32 u[16];
#pragma unroll
    for (int q = 0; q < 16; q++) u[q] = hp[(size_t)idx[q] * 64 + lane];
#pragma unroll
    for (int q = 0; q < 16; q++) {
      a0 = fmaf(w[q], blo(u[q]), a0);
      a1 = fmaf(w[q], bhi(u[q]), a1);
    }
  }
  ((uint32*)z)[(size_t)node * 64 + lane] = pack2(a0, a1);
}

// ---------------- fused MLP: out = BN(lrelu(Z W1 + b1) W2 + b2) [opt lrelu] -----------
// R9-proven: A-tile bulk-staged via global_load_lds with source-side XOR chunk-swizzle;
// B global frag-packed (L2-hot); 3 barriers/block; 3 blocks/CU.
template<int K1>
__global__ __launch_bounds__(256, 3) void fgemm_k(
    const ushort_t* __restrict__ A, const ushort_t* __restrict__ B1t,
    const ushort_t* __restrict__ B2t, const float* __restrict__ bi1,
    const float* __restrict__ sc2, const float* __restrict__ bi2,
    void* __restrict__ out, int lrelu2, int f32out) {
  __shared__ ushort_t S[64 * 264];     // 33 KB: A-tile (swizzled linear) then C1 (stride 264)
  const int tid = threadIdx.x;
  const int lane = tid & 63;
  const int wid = tid >> 6;
  const int m0 = blockIdx.x * 64;
  const int fr = lane & 15;
  const int fk = (lane >> 4) * 8;
  const int er = lane >> 4;
  const int ec = lane & 15;
  constexpr int S1 = K1 / 32;          // K-steps: 4 or 8
  constexpr int CH = K1 / 8;           // 16B chunks per row: 16 or 32
  constexpr int NL = (64 * CH) / 256;  // gload_lds per thread: 4 or 8

  const short8* Bp1 = (const short8*)B1t;   // frag-packed: chunk ((wid*S1+ks)*4+j)*64+lane
  const short8* Bp2 = (const short8*)B2t;

  // ---- phase 0: bulk-stage A-tile (64 x K1) into LDS, source-swizzled ----
#pragma unroll
  for (int l = 0; l < NL; l++) {
    int off16 = l * 256 + tid;          // 16B-chunk index in linear LDS
    int row = off16 / CH;
    int sch = off16 & (CH - 1);
    int lch = sch ^ (row & (CH - 1));   // involution: slot sch holds logical chunk lch
    __builtin_amdgcn_global_load_lds((gptr_t)(A + (size_t)(m0 + row) * K1 + lch * 8),
                                     (lptr_t)(S + (size_t)off16 * 8), 16, 0, 0);
  }

  f32x4 zero = {0.f, 0.f, 0.f, 0.f};
  f32x4 acc[4][4];
#pragma unroll
  for (int i = 0; i < 4; i++)
#pragma unroll
    for (int j = 0; j < 4; j++) acc[i][j] = zero;

  __syncthreads();   // barrier 1: A staged (implicit vmcnt drain)

  // ---- phase 1: Z (64 x K1, LDS) * W1 (K1 x 256, global frag-pack) ----
#pragma unroll 2
  for (int ks = 0; ks < S1; ks++) {
    short8 af[4], bfv[4];
#pragma unroll
    for (int i = 0; i < 4; i++) {
      int row = i * 16 + fr;
      int lc = ks * 4 + (lane >> 4);
      int sch = lc ^ (row & (CH - 1));
      af[i] = *(const short8*)(S + row * K1 + sch * 8);
    }
#pragma unroll
    for (int j = 0; j < 4; j++)
      bfv[j] = Bp1[((wid * S1 + ks) * 4 + j) * 64 + lane];
#pragma unroll
    for (int i = 0; i < 4; i++)
#pragma unroll
      for (int j = 0; j < 4; j++)
        acc[i][j] = __builtin_amdgcn_mfma_f32_16x16x32_bf16(af[i], bfv[j], acc[i][j], 0, 0, 0);
  }

  __syncthreads();   // barrier 2: all waves done reading A before C1 overwrites S

  // C1 = lrelu(acc + b1) -> S (stride 264)
#pragma unroll
  for (int j = 0; j < 4; j++) {
    int col = wid * 64 + j * 16 + ec;
    float b = bi1[col];
#pragma unroll
    for (int i = 0; i < 4; i++) {
#pragma unroll
      for (int r = 0; r < 4; r++) {
        int row = i * 16 + er * 4 + r;
        float v = acc[i][j][r] + b;
        v = (v > 0.f) ? v : 0.01f * v;
        S[row * 264 + col] = f2b(v);
      }
    }
  }
  __syncthreads();   // barrier 3: publish C1

  // ---- phase 2: C1 (64 x 256, LDS) * W2 (256 x 256, global frag-pack) ----
  f32x4 acc2[4][4];
#pragma unroll
  for (int i = 0; i < 4; i++)
#pragma unroll
    for (int j = 0; j < 4; j++) acc2[i][j] = zero;

#pragma unroll 2
  for (int ks = 0; ks < 8; ks++) {
    const int kk = ks * 32;
    short8 af[4], bfv[4];
#pragma unroll
    for (int i = 0; i < 4; i++)
      af[i] = *(const short8*)(S + (i * 16 + fr) * 264 + kk + fk);
#pragma unroll
    for (int j = 0; j < 4; j++)
      bfv[j] = Bp2[((wid * 8 + ks) * 4 + j) * 64 + lane];
#pragma unroll
    for (int i = 0; i < 4; i++)
#pragma unroll
      for (int j = 0; j < 4; j++)
        acc2[i][j] = __builtin_amdgcn_mfma_f32_16x16x32_bf16(af[i], bfv[j], acc2[i][j], 0, 0, 0);
  }

  // epilogue: BN fold (+opt lrelu), store
#pragma unroll
  for (int j = 0; j < 4; j++) {
    int col = wid * 64 + j * 16 + ec;
    float s = sc2[col], b = bi2[col];
#pragma unroll
    for (int i = 0; i < 4; i++) {
#pragma unroll
      for (int r = 0; r < 4; r++) {
        int row = m0 + i * 16 + er * 4 + r;
        float v = acc2[i][j][r] * s + b;
        if (lrelu2) v = (v > 0.f) ? v : 0.01f * v;
        if (row < NN) {
          if (f32out) ((float*)out)[(size_t)row * HID + col] = v;
          else        ((ushort_t*)out)[(size_t)row * HID + col] = f2b(v);
        }
      }
    }
  }
}

extern "C" void kernel_launch(void* const* d_in, const int* in_sizes, int n_in,
                              void* d_out, int out_size, void* d_ws, size_t ws_size,
                              hipStream_t stream) {
  const float* x    = (const float*)d_in[0];
  const int*   src  = (const int*)d_in[1];
  const int*   dst  = (const int*)d_in[2];
  const float* w1_0 = (const float*)d_in[3];
  const float* b1_0 = (const float*)d_in[4];
  const float* w2_0 = (const float*)d_in[5];
  const float* b2_0 = (const float*)d_in[6];
  const float* g0   = (const float*)d_in[7];
  const float* be0  = (const float*)d_in[8];
  const float* m0   = (const float*)d_in[9];
  const float* v0   = (const float*)d_in[10];
  const float* w1_r = (const float*)d_in[11];
  const float* b1_r = (const float*)d_in[12];
  const float* w2_r = (const float*)d_in[13];
  const float* b2_r = (const float*)d_in[14];
  const float* g_r  = (const float*)d_in[15];
  const float* be_r = (const float*)d_in[16];
  const float* m_r  = (const float*)d_in[17];
  const float* v_r  = (const float*)d_in[18];

  char* ws = (char*)d_ws;
  size_t off = 0;
  auto alloc = [&](size_t bytes) {
    void* p = ws + off;
    off = (off + bytes + 255) & ~(size_t)255;
    return p;
  };
  ushort_t* bufA  = (ushort_t*)alloc((size_t)MPAD * HID * 2);
  ushort_t* bufB  = (ushort_t*)alloc((size_t)MPAD * HID * 2);
  ushort_t* xb    = (ushort_t*)alloc((size_t)MPAD * IND * 2);
  int*      rp    = (int*)alloc((NN + 1) * sizeof(int));
  int*      cnt   = (int*)alloc(NN * sizeof(int));
  int*      bsum  = (int*)alloc(NBLK * sizeof(int));
  int*      esrc  = (int*)alloc((size_t)NE * sizeof(int));
  ushort_t* wt    = (ushort_t*)alloc(((size_t)HID * IND + 5 * (size_t)HID * HID) * 2);
  float*    bi1   = (float*)alloc(3 * HID * sizeof(float));
  float*    sc2   = (float*)alloc(3 * HID * sizeof(float));
  float*    bi2   = (float*)alloc(3 * HID * sizeof(float));
  (void)ws_size; (void)in_sizes; (void)n_in; (void)out_size;

  // CSR scratch aliases compute buffers (used strictly before agg/fgemm write them)
  uint32* partial = (uint32*)bufA;     // 64 * 50000 * 4B = 12.8 MB <= 25.6 MB

  ushort_t* w1_0t = wt;
  ushort_t* w2_0t = wt + HID * IND;
  ushort_t* w1r0t = wt + HID * IND + 1 * HID * HID;
  ushort_t* w2r0t = wt + HID * IND + 2 * HID * HID;
  ushort_t* w1r1t = wt + HID * IND + 3 * HID * HID;
  ushort_t* w2r1t = wt + HID * IND + 4 * HID * HID;

  // CSR build (atomic-free, rank recomputed in scatter)
  histp_k<<<NCH * NRG, 256, 0, stream>>>(dst, partial);
  coff_k<<<(NN + 255) / 256, 256, 0, stream>>>(partial, cnt);
  bsum_k<<<NBLK, 1024, 0, stream>>>(cnt, bsum);
  bscan_k<<<1, 64, 0, stream>>>(bsum, rp);
  scan2_k<<<NBLK, 1024, 0, stream>>>(cnt, bsum, rp);
  scat3_k<<<NCH * NRG, 256, 0, stream>>>(src, dst, rp, partial, esrc);

  // weight/BN/input prep
  prep_k<<<dim3(HID, 7), 256, 0, stream>>>(w1_0, w2_0, w1_r, w2_r,
                                           b1_0, b2_0, g0, be0, m0, v0,
                                           b1_r, b2_r, g_r, be_r, m_r, v_r,
                                           wt, bi1, sc2, bi2);
  x2b_k<<<(NN * IND / 2 + 255) / 256, 256, 0, stream>>>(x, xb);

  const int GG = MPAD / 64;  // 782
  // layer 0
  agg128_k<<<NN / 4, 256, 0, stream>>>(xb, rp, esrc, bufA);
  fgemm_k<IND><<<GG, 256, 0, stream>>>(bufA, w1_0t, w2_0t, bi1, sc2, bi2, bufB, 1, 0);
  // layer 1
  agg256_k<<<NN / 4, 256, 0, stream>>>(bufB, rp, esrc, bufA);
  fgemm_k<HID><<<GG, 256, 0, stream>>>(bufA, w1r0t, w2r0t, bi1 + HID, sc2 + HID, bi2 + HID, bufB, 1, 0);
  // layer 2
  agg256_k<<<NN / 4, 256, 0, stream>>>(bufB, rp, esrc, bufA);
  fgemm_k<HID><<<GG, 256, 0, stream>>>(bufA, w1r1t, w2r1t, bi1 + 2 * HID, sc2 + 2 * HID, bi2 + 2 * HID, d_out, 0, 1);
}

// Round 12
// 404.807 us; speedup vs baseline: 1.0147x; 1.0147x over previous
//
#include <hip/hip_runtime.h>
#include <hip/hip_bf16.h>
#include <stdint.h>

#define NN 50000
#define NE 800000
#define IND 128
#define HID 256
#define MPAD 50048      // 782 * 64
#define NBLK 49         // ceil(NN/1024)

// atomic-free CSR build geometry
#define NCH 64          // edge chunks
#define CHSZ 12500      // NE / NCH
#define NRG 8           // dst ranges
#define RGSZ 6250       // NN / NRG (25 KB LDS histogram)

typedef unsigned int uint32;
typedef unsigned short ushort_t;
typedef __attribute__((ext_vector_type(8))) short short8;
typedef __attribute__((ext_vector_type(4))) float f32x4;

typedef const __attribute__((address_space(1))) void* gptr_t;
typedef __attribute__((address_space(3))) void* lptr_t;

__device__ __forceinline__ ushort_t f2b(float f) {
  uint32 u = __float_as_uint(f);
  u = (u + 0x7fffu + ((u >> 16) & 1u)) >> 16;
  return (ushort_t)u;
}
__device__ __forceinline__ float blo(uint32 u) { return __uint_as_float(u << 16); }
__device__ __forceinline__ float bhi(uint32 u) { return __uint_as_float(u & 0xffff0000u); }
__device__ __forceinline__ uint32 pack2(float a, float b) {
  return (uint32)f2b(a) | ((uint32)f2b(b) << 16);
}

// fragment-packed weight layout: 16B chunk per (colgrp wid, kstep ks, frag j, lane),
// lane = ((k&31)>>3)*16 + (col&15). One coalesced 1KB load per B-fragment.
__device__ __forceinline__ int packidx(int col, int k, int Kd) {
  int lane = ((k & 31) >> 3) * 16 + (col & 15);
  int c = (((col >> 6) * (Kd >> 5) + (k >> 5)) * 4 + ((col >> 4) & 3)) * 64 + lane;
  return c * 8 + (k & 7);
}

// ---------------- CSR build (no global atomics, no rnk array) ----------------
__global__ __launch_bounds__(256) void histp_k(const int* __restrict__ dst,
                                               uint32* __restrict__ partial) {
  __shared__ uint32 lh[RGSZ];
  const int c = blockIdx.x & (NCH - 1);
  const int rg = blockIdx.x >> 6;
  const int r0 = rg * RGSZ;
  for (int i = threadIdx.x; i < RGSZ; i += 256) lh[i] = 0;
  __syncthreads();
  const int e0 = c * CHSZ;
  for (int i = threadIdx.x; i < CHSZ; i += 256) {
    int d = dst[e0 + i] - r0;
    if ((unsigned)d < (unsigned)RGSZ) atomicAdd(&lh[d], 1u);
  }
  __syncthreads();
  uint32* po = partial + (size_t)c * NN + r0;
  for (int i = threadIdx.x; i < RGSZ; i += 256) po[i] = lh[i];
}

__global__ void coff_k(uint32* __restrict__ partial, int* __restrict__ cnt) {
  int bin = blockIdx.x * 256 + threadIdx.x;
  if (bin >= NN) return;
  uint32 run = 0;
#pragma unroll
  for (int c = 0; c < NCH; c++) {
    uint32 t = partial[(size_t)c * NN + bin];
    partial[(size_t)c * NN + bin] = run;
    run += t;
  }
  cnt[bin] = (int)run;
}

__global__ void bsum_k(const int* __restrict__ cnt, int* __restrict__ bsum) {
  __shared__ int ws[16];
  const int tid = threadIdx.x, ln = tid & 63, wv = tid >> 6;
  int i = blockIdx.x * 1024 + tid;
  int v = (i < NN) ? cnt[i] : 0;
#pragma unroll
  for (int d = 32; d; d >>= 1) v += __shfl_down(v, d, 64);
  if (ln == 0) ws[wv] = v;
  __syncthreads();
  if (tid < 16) {
    int s = ws[tid];
#pragma unroll
    for (int d = 8; d; d >>= 1) s += __shfl_down(s, d, 64);
    if (tid == 0) bsum[blockIdx.x] = s;
  }
}

__global__ void bscan_k(int* __restrict__ bsum, int* __restrict__ rp) {
  int tid = threadIdx.x;
  int v = (tid < NBLK) ? bsum[tid] : 0;
  int x = v;
#pragma unroll
  for (int d = 1; d < 64; d <<= 1) {
    int t = __shfl_up(x, d, 64);
    if (tid >= d) x += t;
  }
  if (tid < NBLK) bsum[tid] = x - v;
  if (tid == 0) rp[NN] = NE;
}

__global__ void scan2_k(const int* __restrict__ cnt, const int* __restrict__ bsum,
                        int* __restrict__ rp) {
  __shared__ int ws[16];
  const int tid = threadIdx.x, ln = tid & 63, wv = tid >> 6;
  int i = blockIdx.x * 1024 + tid;
  int v = (i < NN) ? cnt[i] : 0;
  int x = v;
#pragma unroll
  for (int d = 1; d < 64; d <<= 1) {
    int t = __shfl_up(x, d, 64);
    if (ln >= d) x += t;
  }
  if (ln == 63) ws[wv] = x;
  __syncthreads();
  if (tid < 16) {
    int s = ws[tid];
#pragma unroll
    for (int d = 1; d < 16; d <<= 1) {
      int t = __shfl_up(s, d, 64);
      if (tid >= d) s += t;
    }
    ws[tid] = s;
  }
  __syncthreads();
  int excl = x - v + (wv ? ws[wv - 1] : 0) + bsum[blockIdx.x];
  if (i < NN) rp[i] = excl;
}

__global__ __launch_bounds__(256) void scat3_k(const int* __restrict__ src,
                                               const int* __restrict__ dst,
                                               const int* __restrict__ rp,
                                               const uint32* __restrict__ partial,
                                               int* __restrict__ esrc) {
  __shared__ int base[RGSZ];     // 25 KB
  __shared__ uint32 lh[RGSZ];    // 25 KB
  const int c = blockIdx.x & (NCH - 1);
  const int rg = blockIdx.x >> 6;
  const int r0 = rg * RGSZ;
  const uint32* po = partial + (size_t)c * NN + r0;
  const int* rpo = rp + r0;
  for (int i = threadIdx.x; i < RGSZ; i += 256) {
    base[i] = rpo[i] + (int)po[i];
    lh[i] = 0;
  }
  __syncthreads();
  const int e0 = c * CHSZ;
  for (int i = threadIdx.x; i < CHSZ; i += 256) {
    int e = e0 + i;
    int d = dst[e] - r0;
    if ((unsigned)d < (unsigned)RGSZ) {
      int r = (int)atomicAdd(&lh[d], 1u);
      esrc[base[d] + r] = src[e];
    }
  }
}

// ---------------- prep: weights (6 transposes -> frag-pack) + BN folding ----------------
__global__ void prep_k(const float* __restrict__ w1_0, const float* __restrict__ w2_0,
                       const float* __restrict__ w1_r, const float* __restrict__ w2_r,
                       const float* b1_0, const float* b2_0, const float* g0,
                       const float* be0, const float* m0, const float* v0,
                       const float* b1_r, const float* b2_r, const float* g_r,
                       const float* be_r, const float* m_r, const float* v_r,
                       ushort_t* __restrict__ wt,
                       float* bi1, float* sc2, float* bi2) {
  const int which = blockIdx.y;
  if (which < 6) {
    const int n = blockIdx.x, k = threadIdx.x;
    const float* w; ushort_t* o; int K = HID;
    switch (which) {
      case 0: w = w1_0; o = wt; K = IND; break;
      case 1: w = w2_0; o = wt + HID * IND; break;
      case 2: w = w1_r; o = wt + HID * IND + 1 * HID * HID; break;
      case 3: w = w2_r; o = wt + HID * IND + 2 * HID * HID; break;
      case 4: w = w1_r + HID * HID; o = wt + HID * IND + 3 * HID * HID; break;
      default: w = w2_r + HID * HID; o = wt + HID * IND + 4 * HID * HID; break;
    }
    if (k < K) o[packidx(n, k, K)] = f2b(w[(size_t)k * HID + n]);
  } else {
    const int l = blockIdx.x;
    if (l >= 3) return;
    const int j = threadIdx.x;
    float b1, b2, g, be, m, v;
    if (l == 0) { b1 = b1_0[j]; b2 = b2_0[j]; g = g0[j]; be = be0[j]; m = m0[j]; v = v0[j]; }
    else { int o = (l - 1) * HID + j; b1 = b1_r[o]; b2 = b2_r[o]; g = g_r[o]; be = be_r[o]; m = m_r[o]; v = v_r[o]; }
    int o = l * HID + j;
    bi1[o] = b1;
    float s = g * rsqrtf(v + 1e-5f);
    sc2[o] = s;
    bi2[o] = (b2 - m) * s + be;
  }
}

// cast x (NN x 128 fp32) -> bf16
__global__ void x2b_k(const float* __restrict__ x, ushort_t* __restrict__ xb) {
  int i = blockIdx.x * 256 + threadIdx.x;
  const int n = NN * IND / 2;
  if (i < n) {
    float2 f = ((const float2*)x)[i];
    ((uint32*)xb)[i] = pack2(f.x, f.y);
  }
}

// ---------------- aggregation: z = h + sum h_j ----------------
// R10-proven: 8-deep gather batches + idx prefetch pipeline + branch-free
// padded-8 tail (clamped dup idx, 0/1 fma weights). R11's 16-deep variant
// regressed (VGPR 44 -> occupancy 40%); 8-deep is the measured sweet spot.
__global__ void agg256_k(const ushort_t* __restrict__ h, const int* __restrict__ rp,
                         const int* __restrict__ esrc, ushort_t* __restrict__ z) {
  int wid = threadIdx.x >> 6, lane = threadIdx.x & 63;
  int node = blockIdx.x * 4 + wid;
  if (node >= NN) return;
  const uint2* hp = (const uint2*)h;
  uint2 v = hp[(size_t)node * 64 + lane];
  float a0 = blo(v.x), a1 = bhi(v.x), a2 = blo(v.y), a3 = bhi(v.y);
  int e0 = rp[node], e1 = rp[node + 1];
  const int nfull = (e1 - e0) >> 3;
  int s[8], sn[8];
  if (nfull > 0) {
#pragma unroll
    for (int q = 0; q < 8; q++) s[q] = esrc[e0 + q];
  }
  for (int b = 0; b < nfull; b++) {
    const int e = e0 + b * 8;
    if (b + 1 < nfull) {
#pragma unroll
      for (int q = 0; q < 8; q++) sn[q] = esrc[e + 8 + q];
    }
    uint2 u[8];
#pragma unroll
    for (int q = 0; q < 8; q++) u[q] = hp[(size_t)s[q] * 64 + lane];
#pragma unroll
    for (int q = 0; q < 8; q++) {
      a0 += blo(u[q].x); a1 += bhi(u[q].x); a2 += blo(u[q].y); a3 += bhi(u[q].y);
    }
#pragma unroll
    for (int q = 0; q < 8; q++) s[q] = sn[q];
  }
  const int e = e0 + nfull * 8;
  if (e < e1) {
    const int last = e1 - 1;
    int idx[8]; float w[8];
#pragma unroll
    for (int q = 0; q < 8; q++) {
      int ee = e + q;
      w[q] = (ee < e1) ? 1.f : 0.f;
      idx[q] = esrc[(ee < e1) ? ee : last];
    }
    uint2 u[8];
#pragma unroll
    for (int q = 0; q < 8; q++) u[q] = hp[(size_t)idx[q] * 64 + lane];
#pragma unroll
    for (int q = 0; q < 8; q++) {
      a0 = fmaf(w[q], blo(u[q].x), a0);
      a1 = fmaf(w[q], bhi(u[q].x), a1);
      a2 = fmaf(w[q], blo(u[q].y), a2);
      a3 = fmaf(w[q], bhi(u[q].y), a3);
    }
  }
  uint2 o; o.x = pack2(a0, a1); o.y = pack2(a2, a3);
  ((uint2*)z)[(size_t)node * 64 + lane] = o;
}

__global__ void agg128_k(const ushort_t* __restrict__ h, const int* __restrict__ rp,
                         const int* __restrict__ esrc, ushort_t* __restrict__ z) {
  int wid = threadIdx.x >> 6, lane = threadIdx.x & 63;
  int node = blockIdx.x * 4 + wid;
  if (node >= NN) return;
  const uint32* hp = (const uint32*)h;
  uint32 v = hp[(size_t)node * 64 + lane];
  float a0 = blo(v), a1 = bhi(v);
  int e0 = rp[node], e1 = rp[node + 1];
  const int nfull = (e1 - e0) >> 3;
  int s[8], sn[8];
  if (nfull > 0) {
#pragma unroll
    for (int q = 0; q < 8; q++) s[q] = esrc[e0 + q];
  }
  for (int b = 0; b < nfull; b++) {
    const int e = e0 + b * 8;
    if (b + 1 < nfull) {
#pragma unroll
      for (int q = 0; q < 8; q++) sn[q] = esrc[e + 8 + q];
    }
    uint32 u[8];
#pragma unroll
    for (int q = 0; q < 8; q++) u[q] = hp[(size_t)s[q] * 64 + lane];
#pragma unroll
    for (int q = 0; q < 8; q++) { a0 += blo(u[q]); a1 += bhi(u[q]); }
#pragma unroll
    for (int q = 0; q < 8; q++) s[q] = sn[q];
  }
  const int e = e0 + nfull * 8;
  if (e < e1) {
    const int last = e1 - 1;
    int idx[8]; float w[8];
#pragma unroll
    for (int q = 0; q < 8; q++) {
      int ee = e + q;
      w[q] = (ee < e1) ? 1.f : 0.f;
      idx[q] = esrc[(ee < e1) ? ee : last];
    }
    uint32 u[8];
#pragma unroll
    for (int q = 0; q < 8; q++) u[q] = hp[(size_t)idx[q] * 64 + lane];
#pragma unroll
    for (int q = 0; q < 8; q++) {
      a0 = fmaf(w[q], blo(u[q]), a0);
      a1 = fmaf(w[q], bhi(u[q]), a1);
    }
  }
  ((uint32*)z)[(size_t)node * 64 + lane] = pack2(a0, a1);
}

// ---------------- fused MLP: out = BN(lrelu(Z W1 + b1) W2 + b2) [opt lrelu] -----------
// R9-proven structure (A-tile LDS-staged via global_load_lds + source-side XOR
// chunk-swizzle; B global frag-packed L2-hot; 3 barriers/block).
// R12: 4 blocks/CU (was 3) — B-loads are latency-bound; A now lives in LDS so
// live VGPR ~115 fits the 128 cap. LDS 33KB x 4 = 132KB <= 160KB.
template<int K1>
__global__ __launch_bounds__(256, 4) void fgemm_k(
    const ushort_t* __restrict__ A, const ushort_t* __restrict__ B1t,
    const ushort_t* __restrict__ B2t, const float* __restrict__ bi1,
    const float* __restrict__ sc2, const float* __restrict__ bi2,
    void* __restrict__ out, int lrelu2, int f32out) {
  __shared__ ushort_t S[64 * 264];     // 33 KB: A-tile (swizzled linear) then C1 (stride 264)
  const int tid = threadIdx.x;
  const int lane = tid & 63;
  const int wid = tid >> 6;
  const int m0 = blockIdx.x * 64;
  const int fr = lane & 15;
  const int fk = (lane >> 4) * 8;
  const int er = lane >> 4;
  const int ec = lane & 15;
  constexpr int S1 = K1 / 32;          // K-steps: 4 or 8
  constexpr int CH = K1 / 8;           // 16B chunks per row: 16 or 32
  constexpr int NL = (64 * CH) / 256;  // gload_lds per thread: 4 or 8

  const short8* Bp1 = (const short8*)B1t;   // frag-packed: chunk ((wid*S1+ks)*4+j)*64+lane
  const short8* Bp2 = (const short8*)B2t;

  // ---- phase 0: bulk-stage A-tile (64 x K1) into LDS, source-swizzled ----
#pragma unroll
  for (int l = 0; l < NL; l++) {
    int off16 = l * 256 + tid;          // 16B-chunk index in linear LDS
    int row = off16 / CH;
    int sch = off16 & (CH - 1);
    int lch = sch ^ (row & (CH - 1));   // involution: slot sch holds logical chunk lch
    __builtin_amdgcn_global_load_lds((gptr_t)(A + (size_t)(m0 + row) * K1 + lch * 8),
                                     (lptr_t)(S + (size_t)off16 * 8), 16, 0, 0);
  }

  f32x4 zero = {0.f, 0.f, 0.f, 0.f};
  f32x4 acc[4][4];
#pragma unroll
  for (int i = 0; i < 4; i++)
#pragma unroll
    for (int j = 0; j < 4; j++) acc[i][j] = zero;

  __syncthreads();   // barrier 1: A staged (implicit vmcnt drain)

  // ---- phase 1: Z (64 x K1, LDS) * W1 (K1 x 256, global frag-pack) ----
#pragma unroll 2
  for (int ks = 0; ks < S1; ks++) {
    short8 af[4], bfv[4];
#pragma unroll
    for (int i = 0; i < 4; i++) {
      int row = i * 16 + fr;
      int lc = ks * 4 + (lane >> 4);
      int sch = lc ^ (row & (CH - 1));
      af[i] = *(const short8*)(S + row * K1 + sch * 8);
    }
#pragma unroll
    for (int j = 0; j < 4; j++)
      bfv[j] = Bp1[((wid * S1 + ks) * 4 + j) * 64 + lane];
#pragma unroll
    for (int i = 0; i < 4; i++)
#pragma unroll
      for (int j = 0; j < 4; j++)
        acc[i][j] = __builtin_amdgcn_mfma_f32_16x16x32_bf16(af[i], bfv[j], acc[i][j], 0, 0, 0);
  }

  __syncthreads();   // barrier 2: all waves done reading A before C1 overwrites S

  // C1 = lrelu(acc + b1) -> S (stride 264)
#pragma unroll
  for (int j = 0; j < 4; j++) {
    int col = wid * 64 + j * 16 + ec;
    float b = bi1[col];
#pragma unroll
    for (int i = 0; i < 4; i++) {
#pragma unroll
      for (int r = 0; r < 4; r++) {
        int row = i * 16 + er * 4 + r;
        float v = acc[i][j][r] + b;
        v = (v > 0.f) ? v : 0.01f * v;
        S[row * 264 + col] = f2b(v);
      }
    }
  }
  __syncthreads();   // barrier 3: publish C1

  // ---- phase 2: C1 (64 x 256, LDS) * W2 (256 x 256, global frag-pack) ----
  f32x4 acc2[4][4];
#pragma unroll
  for (int i = 0; i < 4; i++)
#pragma unroll
    for (int j = 0; j < 4; j++) acc2[i][j] = zero;

#pragma unroll 2
  for (int ks = 0; ks < 8; ks++) {
    const int kk = ks * 32;
    short8 af[4], bfv[4];
#pragma unroll
    for (int i = 0; i < 4; i++)
      af[i] = *(const short8*)(S + (i * 16 + fr) * 264 + kk + fk);
#pragma unroll
    for (int j = 0; j < 4; j++)
      bfv[j] = Bp2[((wid * 8 + ks) * 4 + j) * 64 + lane];
#pragma unroll
    for (int i = 0; i < 4; i++)
#pragma unroll
      for (int j = 0; j < 4; j++)
        acc2[i][j] = __builtin_amdgcn_mfma_f32_16x16x32_bf16(af[i], bfv[j], acc2[i][j], 0, 0, 0);
  }

  // epilogue: BN fold (+opt lrelu), store
#pragma unroll
  for (int j = 0; j < 4; j++) {
    int col = wid * 64 + j * 16 + ec;
    float s = sc2[col], b = bi2[col];
#pragma unroll
    for (int i = 0; i < 4; i++) {
#pragma unroll
      for (int r = 0; r < 4; r++) {
        int row = m0 + i * 16 + er * 4 + r;
        float v = acc2[i][j][r] * s + b;
        if (lrelu2) v = (v > 0.f) ? v : 0.01f * v;
        if (row < NN) {
          if (f32out) ((float*)out)[(size_t)row * HID + col] = v;
          else        ((ushort_t*)out)[(size_t)row * HID + col] = f2b(v);
        }
      }
    }
  }
}

extern "C" void kernel_launch(void* const* d_in, const int* in_sizes, int n_in,
                              void* d_out, int out_size, void* d_ws, size_t ws_size,
                              hipStream_t stream) {
  const float* x    = (const float*)d_in[0];
  const int*   src  = (const int*)d_in[1];
  const int*   dst  = (const int*)d_in[2];
  const float* w1_0 = (const float*)d_in[3];
  const float* b1_0 = (const float*)d_in[4];
  const float* w2_0 = (const float*)d_in[5];
  const float* b2_0 = (const float*)d_in[6];
  const float* g0   = (const float*)d_in[7];
  const float* be0  = (const float*)d_in[8];
  const float* m0   = (const float*)d_in[9];
  const float* v0   = (const float*)d_in[10];
  const float* w1_r = (const float*)d_in[11];
  const float* b1_r = (const float*)d_in[12];
  const float* w2_r = (const float*)d_in[13];
  const float* b2_r = (const float*)d_in[14];
  const float* g_r  = (const float*)d_in[15];
  const float* be_r = (const float*)d_in[16];
  const float* m_r  = (const float*)d_in[17];
  const float* v_r  = (const float*)d_in[18];

  char* ws = (char*)d_ws;
  size_t off = 0;
  auto alloc = [&](size_t bytes) {
    void* p = ws + off;
    off = (off + bytes + 255) & ~(size_t)255;
    return p;
  };
  ushort_t* bufA  = (ushort_t*)alloc((size_t)MPAD * HID * 2);
  ushort_t* bufB  = (ushort_t*)alloc((size_t)MPAD * HID * 2);
  ushort_t* xb    = (ushort_t*)alloc((size_t)MPAD * IND * 2);
  int*      rp    = (int*)alloc((NN + 1) * sizeof(int));
  int*      cnt   = (int*)alloc(NN * sizeof(int));
  int*      bsum  = (int*)alloc(NBLK * sizeof(int));
  int*      esrc  = (int*)alloc((size_t)NE * sizeof(int));
  ushort_t* wt    = (ushort_t*)alloc(((size_t)HID * IND + 5 * (size_t)HID * HID) * 2);
  float*    bi1   = (float*)alloc(3 * HID * sizeof(float));
  float*    sc2   = (float*)alloc(3 * HID * sizeof(float));
  float*    bi2   = (float*)alloc(3 * HID * sizeof(float));
  (void)ws_size; (void)in_sizes; (void)n_in; (void)out_size;

  // CSR scratch aliases compute buffers (used strictly before agg/fgemm write them)
  uint32* partial = (uint32*)bufA;     // 64 * 50000 * 4B = 12.8 MB <= 25.6 MB

  ushort_t* w1_0t = wt;
  ushort_t* w2_0t = wt + HID * IND;
  ushort_t* w1r0t = wt + HID * IND + 1 * HID * HID;
  ushort_t* w2r0t = wt + HID * IND + 2 * HID * HID;
  ushort_t* w1r1t = wt + HID * IND + 3 * HID * HID;
  ushort_t* w2r1t = wt + HID * IND + 4 * HID * HID;

  // CSR build (atomic-free, rank recomputed in scatter)
  histp_k<<<NCH * NRG, 256, 0, stream>>>(dst, partial);
  coff_k<<<(NN + 255) / 256, 256, 0, stream>>>(partial, cnt);
  bsum_k<<<NBLK, 1024, 0, stream>>>(cnt, bsum);
  bscan_k<<<1, 64, 0, stream>>>(bsum, rp);
  scan2_k<<<NBLK, 1024, 0, stream>>>(cnt, bsum, rp);
  scat3_k<<<NCH * NRG, 256, 0, stream>>>(src, dst, rp, partial, esrc);

  // weight/BN/input prep
  prep_k<<<dim3(HID, 7), 256, 0, stream>>>(w1_0, w2_0, w1_r, w2_r,
                                           b1_0, b2_0, g0, be0, m0, v0,
                                           b1_r, b2_r, g_r, be_r, m_r, v_r,
                                           wt, bi1, sc2, bi2);
  x2b_k<<<(NN * IND / 2 + 255) / 256, 256, 0, stream>>>(x, xb);

  const int GG = MPAD / 64;  // 782
  // layer 0
  agg128_k<<<NN / 4, 256, 0, stream>>>(xb, rp, esrc, bufA);
  fgemm_k<IND><<<GG, 256, 0, stream>>>(bufA, w1_0t, w2_0t, bi1, sc2, bi2, bufB, 1, 0);
  // layer 1
  agg256_k<<<NN / 4, 256, 0, stream>>>(bufB, rp, esrc, bufA);
  fgemm_k<HID><<<GG, 256, 0, stream>>>(bufA, w1r0t, w2r0t, bi1 + HID, sc2 + HID, bi2 + HID, bufB, 1, 0);
  // layer 2
  agg256_k<<<NN / 4, 256, 0, stream>>>(bufB, rp, esrc, bufA);
  fgemm_k<HID><<<GG, 256, 0, stream>>>(bufA, w1r1t, w2r1t, bi1 + 2 * HID, sc2 + 2 * HID, bi2 + 2 * HID, d_out, 0, 1);
}

// Round 13
// 389.819 us; speedup vs baseline: 1.0537x; 1.0384x over previous
//
#include <hip/hip_runtime.h>
#include <hip/hip_bf16.h>
#include <stdint.h>

#define NN 50000
#define NE 800000
#define IND 128
#define HID 256
#define MPAD 50048      // 782 * 64
#define NBLK 49         // ceil(NN/1024)

// atomic-free CSR build geometry
#define NCH 64          // edge chunks
#define CHSZ 12500      // NE / NCH
#define NRG 8           // dst ranges
#define RGSZ 6250       // NN / NRG (25 KB LDS histogram)

typedef unsigned int uint32;
typedef unsigned short ushort_t;
typedef __attribute__((ext_vector_type(8))) short short8;
typedef __attribute__((ext_vector_type(4))) float f32x4;

typedef const __attribute__((address_space(1))) void* gptr_t;
typedef __attribute__((address_space(3))) void* lptr_t;

__device__ __forceinline__ ushort_t f2b(float f) {
  uint32 u = __float_as_uint(f);
  u = (u + 0x7fffu + ((u >> 16) & 1u)) >> 16;
  return (ushort_t)u;
}
__device__ __forceinline__ float blo(uint32 u) { return __uint_as_float(u << 16); }
__device__ __forceinline__ float bhi(uint32 u) { return __uint_as_float(u & 0xffff0000u); }
__device__ __forceinline__ uint32 pack2(float a, float b) {
  return (uint32)f2b(a) | ((uint32)f2b(b) << 16);
}

// fragment-packed weight layout: 16B chunk per (colgrp wid, kstep ks, frag j, lane),
// lane = ((k&31)>>3)*16 + (col&15). One coalesced 1KB load per B-fragment.
__device__ __forceinline__ int packidx(int col, int k, int Kd) {
  int lane = ((k & 31) >> 3) * 16 + (col & 15);
  int c = (((col >> 6) * (Kd >> 5) + (k >> 5)) * 4 + ((col >> 4) & 3)) * 64 + lane;
  return c * 8 + (k & 7);
}

// ---------------- CSR build (no global atomics, no rnk array) ----------------
__global__ __launch_bounds__(256) void histp_k(const int* __restrict__ dst,
                                               uint32* __restrict__ partial) {
  __shared__ uint32 lh[RGSZ];
  const int c = blockIdx.x & (NCH - 1);
  const int rg = blockIdx.x >> 6;
  const int r0 = rg * RGSZ;
  for (int i = threadIdx.x; i < RGSZ; i += 256) lh[i] = 0;
  __syncthreads();
  const int e0 = c * CHSZ;
  for (int i = threadIdx.x; i < CHSZ; i += 256) {
    int d = dst[e0 + i] - r0;
    if ((unsigned)d < (unsigned)RGSZ) atomicAdd(&lh[d], 1u);
  }
  __syncthreads();
  uint32* po = partial + (size_t)c * NN + r0;
  for (int i = threadIdx.x; i < RGSZ; i += 256) po[i] = lh[i];
}

__global__ void coff_k(uint32* __restrict__ partial, int* __restrict__ cnt) {
  int bin = blockIdx.x * 256 + threadIdx.x;
  if (bin >= NN) return;
  uint32 run = 0;
#pragma unroll
  for (int c = 0; c < NCH; c++) {
    uint32 t = partial[(size_t)c * NN + bin];
    partial[(size_t)c * NN + bin] = run;
    run += t;
  }
  cnt[bin] = (int)run;
}

__global__ void bsum_k(const int* __restrict__ cnt, int* __restrict__ bsum) {
  __shared__ int ws[16];
  const int tid = threadIdx.x, ln = tid & 63, wv = tid >> 6;
  int i = blockIdx.x * 1024 + tid;
  int v = (i < NN) ? cnt[i] : 0;
#pragma unroll
  for (int d = 32; d; d >>= 1) v += __shfl_down(v, d, 64);
  if (ln == 0) ws[wv] = v;
  __syncthreads();
  if (tid < 16) {
    int s = ws[tid];
#pragma unroll
    for (int d = 8; d; d >>= 1) s += __shfl_down(s, d, 64);
    if (tid == 0) bsum[blockIdx.x] = s;
  }
}

__global__ void bscan_k(int* __restrict__ bsum, int* __restrict__ rp) {
  int tid = threadIdx.x;
  int v = (tid < NBLK) ? bsum[tid] : 0;
  int x = v;
#pragma unroll
  for (int d = 1; d < 64; d <<= 1) {
    int t = __shfl_up(x, d, 64);
    if (tid >= d) x += t;
  }
  if (tid < NBLK) bsum[tid] = x - v;
  if (tid == 0) rp[NN] = NE;
}

__global__ void scan2_k(const int* __restrict__ cnt, const int* __restrict__ bsum,
                        int* __restrict__ rp) {
  __shared__ int ws[16];
  const int tid = threadIdx.x, ln = tid & 63, wv = tid >> 6;
  int i = blockIdx.x * 1024 + tid;
  int v = (i < NN) ? cnt[i] : 0;
  int x = v;
#pragma unroll
  for (int d = 1; d < 64; d <<= 1) {
    int t = __shfl_up(x, d, 64);
    if (ln >= d) x += t;
  }
  if (ln == 63) ws[wv] = x;
  __syncthreads();
  if (tid < 16) {
    int s = ws[tid];
#pragma unroll
    for (int d = 1; d < 16; d <<= 1) {
      int t = __shfl_up(s, d, 64);
      if (tid >= d) s += t;
    }
    ws[tid] = s;
  }
  __syncthreads();
  int excl = x - v + (wv ? ws[wv - 1] : 0) + bsum[blockIdx.x];
  if (i < NN) rp[i] = excl;
}

__global__ __launch_bounds__(256) void scat3_k(const int* __restrict__ src,
                                               const int* __restrict__ dst,
                                               const int* __restrict__ rp,
                                               const uint32* __restrict__ partial,
                                               int* __restrict__ esrc) {
  __shared__ int base[RGSZ];     // 25 KB
  __shared__ uint32 lh[RGSZ];    // 25 KB
  const int c = blockIdx.x & (NCH - 1);
  const int rg = blockIdx.x >> 6;
  const int r0 = rg * RGSZ;
  const uint32* po = partial + (size_t)c * NN + r0;
  const int* rpo = rp + r0;
  for (int i = threadIdx.x; i < RGSZ; i += 256) {
    base[i] = rpo[i] + (int)po[i];
    lh[i] = 0;
  }
  __syncthreads();
  const int e0 = c * CHSZ;
  for (int i = threadIdx.x; i < CHSZ; i += 256) {
    int e = e0 + i;
    int d = dst[e] - r0;
    if ((unsigned)d < (unsigned)RGSZ) {
      int r = (int)atomicAdd(&lh[d], 1u);
      esrc[base[d] + r] = src[e];
    }
  }
}

// ---------------- prep: weights (6 transposes -> frag-pack) + BN folding ----------------
__global__ void prep_k(const float* __restrict__ w1_0, const float* __restrict__ w2_0,
                       const float* __restrict__ w1_r, const float* __restrict__ w2_r,
                       const float* b1_0, const float* b2_0, const float* g0,
                       const float* be0, const float* m0, const float* v0,
                       const float* b1_r, const float* b2_r, const float* g_r,
                       const float* be_r, const float* m_r, const float* v_r,
                       ushort_t* __restrict__ wt,
                       float* bi1, float* sc2, float* bi2) {
  const int which = blockIdx.y;
  if (which < 6) {
    const int n = blockIdx.x, k = threadIdx.x;
    const float* w; ushort_t* o; int K = HID;
    switch (which) {
      case 0: w = w1_0; o = wt; K = IND; break;
      case 1: w = w2_0; o = wt + HID * IND; break;
      case 2: w = w1_r; o = wt + HID * IND + 1 * HID * HID; break;
      case 3: w = w2_r; o = wt + HID * IND + 2 * HID * HID; break;
      case 4: w = w1_r + HID * HID; o = wt + HID * IND + 3 * HID * HID; break;
      default: w = w2_r + HID * HID; o = wt + HID * IND + 4 * HID * HID; break;
    }
    if (k < K) o[packidx(n, k, K)] = f2b(w[(size_t)k * HID + n]);
  } else {
    const int l = blockIdx.x;
    if (l >= 3) return;
    const int j = threadIdx.x;
    float b1, b2, g, be, m, v;
    if (l == 0) { b1 = b1_0[j]; b2 = b2_0[j]; g = g0[j]; be = be0[j]; m = m0[j]; v = v0[j]; }
    else { int o = (l - 1) * HID + j; b1 = b1_r[o]; b2 = b2_r[o]; g = g_r[o]; be = be_r[o]; m = m_r[o]; v = v_r[o]; }
    int o = l * HID + j;
    bi1[o] = b1;
    float s = g * rsqrtf(v + 1e-5f);
    sc2[o] = s;
    bi2[o] = (b2 - m) * s + be;
  }
}

// cast x (NN x 128 fp32) -> bf16
__global__ void x2b_k(const float* __restrict__ x, ushort_t* __restrict__ xb) {
  int i = blockIdx.x * 256 + threadIdx.x;
  const int n = NN * IND / 2;
  if (i < n) {
    float2 f = ((const float2*)x)[i];
    ((uint32*)xb)[i] = pack2(f.x, f.y);
  }
}

// ---------------- aggregation: z = h + sum h_j ----------------
// R10-proven: 8-deep gather batches + idx prefetch pipeline + branch-free
// padded-8 tail (clamped dup idx, 0/1 fma weights). R11's 16-deep variant
// regressed (VGPR 44 -> occupancy 40%); 8-deep is the measured sweet spot.
__global__ void agg256_k(const ushort_t* __restrict__ h, const int* __restrict__ rp,
                         const int* __restrict__ esrc, ushort_t* __restrict__ z) {
  int wid = threadIdx.x >> 6, lane = threadIdx.x & 63;
  int node = blockIdx.x * 4 + wid;
  if (node >= NN) return;
  const uint2* hp = (const uint2*)h;
  uint2 v = hp[(size_t)node * 64 + lane];
  float a0 = blo(v.x), a1 = bhi(v.x), a2 = blo(v.y), a3 = bhi(v.y);
  int e0 = rp[node], e1 = rp[node + 1];
  const int nfull = (e1 - e0) >> 3;
  int s[8], sn[8];
  if (nfull > 0) {
#pragma unroll
    for (int q = 0; q < 8; q++) s[q] = esrc[e0 + q];
  }
  for (int b = 0; b < nfull; b++) {
    const int e = e0 + b * 8;
    if (b + 1 < nfull) {
#pragma unroll
      for (int q = 0; q < 8; q++) sn[q] = esrc[e + 8 + q];
    }
    uint2 u[8];
#pragma unroll
    for (int q = 0; q < 8; q++) u[q] = hp[(size_t)s[q] * 64 + lane];
#pragma unroll
    for (int q = 0; q < 8; q++) {
      a0 += blo(u[q].x); a1 += bhi(u[q].x); a2 += blo(u[q].y); a3 += bhi(u[q].y);
    }
#pragma unroll
    for (int q = 0; q < 8; q++) s[q] = sn[q];
  }
  const int e = e0 + nfull * 8;
  if (e < e1) {
    const int last = e1 - 1;
    int idx[8]; float w[8];
#pragma unroll
    for (int q = 0; q < 8; q++) {
      int ee = e + q;
      w[q] = (ee < e1) ? 1.f : 0.f;
      idx[q] = esrc[(ee < e1) ? ee : last];
    }
    uint2 u[8];
#pragma unroll
    for (int q = 0; q < 8; q++) u[q] = hp[(size_t)idx[q] * 64 + lane];
#pragma unroll
    for (int q = 0; q < 8; q++) {
      a0 = fmaf(w[q], blo(u[q].x), a0);
      a1 = fmaf(w[q], bhi(u[q].x), a1);
      a2 = fmaf(w[q], blo(u[q].y), a2);
      a3 = fmaf(w[q], bhi(u[q].y), a3);
    }
  }
  uint2 o; o.x = pack2(a0, a1); o.y = pack2(a2, a3);
  ((uint2*)z)[(size_t)node * 64 + lane] = o;
}

__global__ void agg128_k(const ushort_t* __restrict__ h, const int* __restrict__ rp,
                         const int* __restrict__ esrc, ushort_t* __restrict__ z) {
  int wid = threadIdx.x >> 6, lane = threadIdx.x & 63;
  int node = blockIdx.x * 4 + wid;
  if (node >= NN) return;
  const uint32* hp = (const uint32*)h;
  uint32 v = hp[(size_t)node * 64 + lane];
  float a0 = blo(v), a1 = bhi(v);
  int e0 = rp[node], e1 = rp[node + 1];
  const int nfull = (e1 - e0) >> 3;
  int s[8], sn[8];
  if (nfull > 0) {
#pragma unroll
    for (int q = 0; q < 8; q++) s[q] = esrc[e0 + q];
  }
  for (int b = 0; b < nfull; b++) {
    const int e = e0 + b * 8;
    if (b + 1 < nfull) {
#pragma unroll
      for (int q = 0; q < 8; q++) sn[q] = esrc[e + 8 + q];
    }
    uint32 u[8];
#pragma unroll
    for (int q = 0; q < 8; q++) u[q] = hp[(size_t)s[q] * 64 + lane];
#pragma unroll
    for (int q = 0; q < 8; q++) { a0 += blo(u[q]); a1 += bhi(u[q]); }
#pragma unroll
    for (int q = 0; q < 8; q++) s[q] = sn[q];
  }
  const int e = e0 + nfull * 8;
  if (e < e1) {
    const int last = e1 - 1;
    int idx[8]; float w[8];
#pragma unroll
    for (int q = 0; q < 8; q++) {
      int ee = e + q;
      w[q] = (ee < e1) ? 1.f : 0.f;
      idx[q] = esrc[(ee < e1) ? ee : last];
    }
    uint32 u[8];
#pragma unroll
    for (int q = 0; q < 8; q++) u[q] = hp[(size_t)idx[q] * 64 + lane];
#pragma unroll
    for (int q = 0; q < 8; q++) {
      a0 = fmaf(w[q], blo(u[q]), a0);
      a1 = fmaf(w[q], bhi(u[q]), a1);
    }
  }
  ((uint32*)z)[(size_t)node * 64 + lane] = pack2(a0, a1);
}

// ---------------- fused MLP: out = BN(lrelu(Z W1 + b1) W2 + b2) [opt lrelu] -----------
// R9-proven GEMM structure (A-tile LDS-staged, source-swizzled; B global
// frag-packed; 4 blocks/CU). R13: coalesced epilogue — BN-folded C2 repacked
// through S (dead after phase 2), then streamed out row-major: bf16 = 8B/lane
// uint2 (512B segments), f32 = 16B/lane f32x4 in two 32-row halves. Replaces
// 16 scalar 2B/4B stores per thread (32B segments, 16x request count).
template<int K1>
__global__ __launch_bounds__(256, 4) void fgemm_k(
    const ushort_t* __restrict__ A, const ushort_t* __restrict__ B1t,
    const ushort_t* __restrict__ B2t, const float* __restrict__ bi1,
    const float* __restrict__ sc2, const float* __restrict__ bi2,
    void* __restrict__ out, int lrelu2, int f32out) {
  __shared__ __attribute__((aligned(16))) ushort_t S[64 * 264];  // 33 KB
  const int tid = threadIdx.x;
  const int lane = tid & 63;
  const int wid = tid >> 6;
  const int m0 = blockIdx.x * 64;
  const int fr = lane & 15;
  const int fk = (lane >> 4) * 8;
  const int er = lane >> 4;
  const int ec = lane & 15;
  constexpr int S1 = K1 / 32;          // K-steps: 4 or 8
  constexpr int CH = K1 / 8;           // 16B chunks per row: 16 or 32
  constexpr int NL = (64 * CH) / 256;  // gload_lds per thread: 4 or 8

  const short8* Bp1 = (const short8*)B1t;   // frag-packed: chunk ((wid*S1+ks)*4+j)*64+lane
  const short8* Bp2 = (const short8*)B2t;

  // ---- phase 0: bulk-stage A-tile (64 x K1) into LDS, source-swizzled ----
#pragma unroll
  for (int l = 0; l < NL; l++) {
    int off16 = l * 256 + tid;          // 16B-chunk index in linear LDS
    int row = off16 / CH;
    int sch = off16 & (CH - 1);
    int lch = sch ^ (row & (CH - 1));   // involution: slot sch holds logical chunk lch
    __builtin_amdgcn_global_load_lds((gptr_t)(A + (size_t)(m0 + row) * K1 + lch * 8),
                                     (lptr_t)(S + (size_t)off16 * 8), 16, 0, 0);
  }

  f32x4 zero = {0.f, 0.f, 0.f, 0.f};
  f32x4 acc[4][4];
#pragma unroll
  for (int i = 0; i < 4; i++)
#pragma unroll
    for (int j = 0; j < 4; j++) acc[i][j] = zero;

  __syncthreads();   // barrier 1: A staged (implicit vmcnt drain)

  // ---- phase 1: Z (64 x K1, LDS) * W1 (K1 x 256, global frag-pack) ----
#pragma unroll 2
  for (int ks = 0; ks < S1; ks++) {
    short8 af[4], bfv[4];
#pragma unroll
    for (int i = 0; i < 4; i++) {
      int row = i * 16 + fr;
      int lc = ks * 4 + (lane >> 4);
      int sch = lc ^ (row & (CH - 1));
      af[i] = *(const short8*)(S + row * K1 + sch * 8);
    }
#pragma unroll
    for (int j = 0; j < 4; j++)
      bfv[j] = Bp1[((wid * S1 + ks) * 4 + j) * 64 + lane];
#pragma unroll
    for (int i = 0; i < 4; i++)
#pragma unroll
      for (int j = 0; j < 4; j++)
        acc[i][j] = __builtin_amdgcn_mfma_f32_16x16x32_bf16(af[i], bfv[j], acc[i][j], 0, 0, 0);
  }

  __syncthreads();   // barrier 2: all waves done reading A before C1 overwrites S

  // C1 = lrelu(acc + b1) -> S (stride 264)
#pragma unroll
  for (int j = 0; j < 4; j++) {
    int col = wid * 64 + j * 16 + ec;
    float b = bi1[col];
#pragma unroll
    for (int i = 0; i < 4; i++) {
#pragma unroll
      for (int r = 0; r < 4; r++) {
        int row = i * 16 + er * 4 + r;
        float v = acc[i][j][r] + b;
        v = (v > 0.f) ? v : 0.01f * v;
        S[row * 264 + col] = f2b(v);
      }
    }
  }
  __syncthreads();   // barrier 3: publish C1

  // ---- phase 2: C1 (64 x 256, LDS) * W2 (256 x 256, global frag-pack) ----
  f32x4 acc2[4][4];
#pragma unroll
  for (int i = 0; i < 4; i++)
#pragma unroll
    for (int j = 0; j < 4; j++) acc2[i][j] = zero;

#pragma unroll 2
  for (int ks = 0; ks < 8; ks++) {
    const int kk = ks * 32;
    short8 af[4], bfv[4];
#pragma unroll
    for (int i = 0; i < 4; i++)
      af[i] = *(const short8*)(S + (i * 16 + fr) * 264 + kk + fk);
#pragma unroll
    for (int j = 0; j < 4; j++)
      bfv[j] = Bp2[((wid * 8 + ks) * 4 + j) * 64 + lane];
#pragma unroll
    for (int i = 0; i < 4; i++)
#pragma unroll
      for (int j = 0; j < 4; j++)
        acc2[i][j] = __builtin_amdgcn_mfma_f32_16x16x32_bf16(af[i], bfv[j], acc2[i][j], 0, 0, 0);
  }

  __syncthreads();   // barrier 4: C1 reads done; S reusable for the repack

  // ---- epilogue: BN fold (+opt lrelu), repack via S, coalesced store ----
  if (!f32out) {
#pragma unroll
    for (int j = 0; j < 4; j++) {
      int col = wid * 64 + j * 16 + ec;
      float s = sc2[col], b = bi2[col];
#pragma unroll
      for (int i = 0; i < 4; i++) {
#pragma unroll
        for (int r = 0; r < 4; r++) {
          int row = i * 16 + er * 4 + r;
          float v = acc2[i][j][r] * s + b;
          if (lrelu2) v = (v > 0.f) ? v : 0.01f * v;
          S[row * 264 + col] = f2b(v);
        }
      }
    }
    __syncthreads();
    // wave wid -> rows wid*16..+15; lane stores 8B (4 ushorts), 512B/row segment
#pragma unroll
    for (int rr = 0; rr < 16; rr++) {
      int row = wid * 16 + rr;
      int grow = m0 + row;
      if (grow < NN) {
        uint2 val;
        val.x = *(const uint32*)(S + row * 264 + lane * 4);
        val.y = *(const uint32*)(S + row * 264 + lane * 4 + 2);
        *(uint2*)((ushort_t*)out + (size_t)grow * HID + lane * 4) = val;
      }
    }
  } else {
    float* Sf = (float*)S;   // [32][264] f32 per half (33792 B <= 67584 B)
#pragma unroll
    for (int half = 0; half < 2; half++) {
#pragma unroll
      for (int j = 0; j < 4; j++) {
        int col = wid * 64 + j * 16 + ec;
        float s = sc2[col], b = bi2[col];
#pragma unroll
        for (int i2 = 0; i2 < 2; i2++) {
          int i = half * 2 + i2;
#pragma unroll
          for (int r = 0; r < 4; r++) {
            int row = i2 * 16 + er * 4 + r;   // 0..31 within half
            float v = acc2[i][j][r] * s + b;
            if (lrelu2) v = (v > 0.f) ? v : 0.01f * v;
            Sf[row * 264 + col] = v;
          }
        }
      }
      __syncthreads();
      // wave wid -> 8 rows; lane stores 16B f32x4, 1KB/row segment
#pragma unroll
      for (int rr = 0; rr < 8; rr++) {
        int row = wid * 8 + rr;              // 0..31
        int grow = m0 + half * 32 + row;
        if (grow < NN) {
          f32x4 val = *(const f32x4*)(Sf + row * 264 + lane * 4);
          *(f32x4*)((float*)out + (size_t)grow * HID + lane * 4) = val;
        }
      }
      if (half == 0) __syncthreads();   // drain reads before half-1 overwrites Sf
    }
  }
}

extern "C" void kernel_launch(void* const* d_in, const int* in_sizes, int n_in,
                              void* d_out, int out_size, void* d_ws, size_t ws_size,
                              hipStream_t stream) {
  const float* x    = (const float*)d_in[0];
  const int*   src  = (const int*)d_in[1];
  const int*   dst  = (const int*)d_in[2];
  const float* w1_0 = (const float*)d_in[3];
  const float* b1_0 = (const float*)d_in[4];
  const float* w2_0 = (const float*)d_in[5];
  const float* b2_0 = (const float*)d_in[6];
  const float* g0   = (const float*)d_in[7];
  const float* be0  = (const float*)d_in[8];
  const float* m0   = (const float*)d_in[9];
  const float* v0   = (const float*)d_in[10];
  const float* w1_r = (const float*)d_in[11];
  const float* b1_r = (const float*)d_in[12];
  const float* w2_r = (const float*)d_in[13];
  const float* b2_r = (const float*)d_in[14];
  const float* g_r  = (const float*)d_in[15];
  const float* be_r = (const float*)d_in[16];
  const float* m_r  = (const float*)d_in[17];
  const float* v_r  = (const float*)d_in[18];

  char* ws = (char*)d_ws;
  size_t off = 0;
  auto alloc = [&](size_t bytes) {
    void* p = ws + off;
    off = (off + bytes + 255) & ~(size_t)255;
    return p;
  };
  ushort_t* bufA  = (ushort_t*)alloc((size_t)MPAD * HID * 2);
  ushort_t* bufB  = (ushort_t*)alloc((size_t)MPAD * HID * 2);
  ushort_t* xb    = (ushort_t*)alloc((size_t)MPAD * IND * 2);
  int*      rp    = (int*)alloc((NN + 1) * sizeof(int));
  int*      cnt   = (int*)alloc(NN * sizeof(int));
  int*      bsum  = (int*)alloc(NBLK * sizeof(int));
  int*      esrc  = (int*)alloc((size_t)NE * sizeof(int));
  ushort_t* wt    = (ushort_t*)alloc(((size_t)HID * IND + 5 * (size_t)HID * HID) * 2);
  float*    bi1   = (float*)alloc(3 * HID * sizeof(float));
  float*    sc2   = (float*)alloc(3 * HID * sizeof(float));
  float*    bi2   = (float*)alloc(3 * HID * sizeof(float));
  (void)ws_size; (void)in_sizes; (void)n_in; (void)out_size;

  // CSR scratch aliases compute buffers (used strictly before agg/fgemm write them)
  uint32* partial = (uint32*)bufA;     // 64 * 50000 * 4B = 12.8 MB <= 25.6 MB

  ushort_t* w1_0t = wt;
  ushort_t* w2_0t = wt + HID * IND;
  ushort_t* w1r0t = wt + HID * IND + 1 * HID * HID;
  ushort_t* w2r0t = wt + HID * IND + 2 * HID * HID;
  ushort_t* w1r1t = wt + HID * IND + 3 * HID * HID;
  ushort_t* w2r1t = wt + HID * IND + 4 * HID * HID;

  // CSR build (atomic-free, rank recomputed in scatter)
  histp_k<<<NCH * NRG, 256, 0, stream>>>(dst, partial);
  coff_k<<<(NN + 255) / 256, 256, 0, stream>>>(partial, cnt);
  bsum_k<<<NBLK, 1024, 0, stream>>>(cnt, bsum);
  bscan_k<<<1, 64, 0, stream>>>(bsum, rp);
  scan2_k<<<NBLK, 1024, 0, stream>>>(cnt, bsum, rp);
  scat3_k<<<NCH * NRG, 256, 0, stream>>>(src, dst, rp, partial, esrc);

  // weight/BN/input prep
  prep_k<<<dim3(HID, 7), 256, 0, stream>>>(w1_0, w2_0, w1_r, w2_r,
                                           b1_0, b2_0, g0, be0, m0, v0,
                                           b1_r, b2_r, g_r, be_r, m_r, v_r,
                                           wt, bi1, sc2, bi2);
  x2b_k<<<(NN * IND / 2 + 255) / 256, 256, 0, stream>>>(x, xb);

  const int GG = MPAD / 64;  // 782
  // layer 0
  agg128_k<<<NN / 4, 256, 0, stream>>>(xb, rp, esrc, bufA);
  fgemm_k<IND><<<GG, 256, 0, stream>>>(bufA, w1_0t, w2_0t, bi1, sc2, bi2, bufB, 1, 0);
  // layer 1
  agg256_k<<<NN / 4, 256, 0, stream>>>(bufB, rp, esrc, bufA);
  fgemm_k<HID><<<GG, 256, 0, stream>>>(bufA, w1r0t, w2r0t, bi1 + HID, sc2 + HID, bi2 + HID, bufB, 1, 0);
  // layer 2
  agg256_k<<<NN / 4, 256, 0, stream>>>(bufB, rp, esrc, bufA);
  fgemm_k<HID><<<GG, 256, 0, stream>>>(bufA, w1r1t, w2r1t, bi1 + 2 * HID, sc2 + 2 * HID, bi2 + 2 * HID, d_out, 0, 1);
}

// Round 14
// 383.795 us; speedup vs baseline: 1.0703x; 1.0157x over previous
//
#include <hip/hip_runtime.h>
#include <hip/hip_bf16.h>
#include <stdint.h>

#define NN 50000
#define NE 800000
#define IND 128
#define HID 256
#define MPAD 50048      // 782 * 64
#define NBLK 49         // ceil(NN/1024)

// atomic-free CSR build geometry
#define NCH 64          // edge chunks
#define CHSZ 12500      // NE / NCH
#define NRG 8           // dst ranges
#define RGSZ 6250       // NN / NRG (25 KB LDS histogram)

typedef unsigned int uint32;
typedef unsigned short ushort_t;
typedef __attribute__((ext_vector_type(8))) short short8;
typedef __attribute__((ext_vector_type(4))) float f32x4;

typedef const __attribute__((address_space(1))) void* gptr_t;
typedef __attribute__((address_space(3))) void* lptr_t;

__device__ __forceinline__ ushort_t f2b(float f) {
  uint32 u = __float_as_uint(f);
  u = (u + 0x7fffu + ((u >> 16) & 1u)) >> 16;
  return (ushort_t)u;
}
__device__ __forceinline__ float blo(uint32 u) { return __uint_as_float(u << 16); }
__device__ __forceinline__ float bhi(uint32 u) { return __uint_as_float(u & 0xffff0000u); }
__device__ __forceinline__ uint32 pack2(float a, float b) {
  return (uint32)f2b(a) | ((uint32)f2b(b) << 16);
}

// fragment-packed weight layout: 16B chunk per (colgrp wid, kstep ks, frag j, lane),
// lane = ((k&31)>>3)*16 + (col&15). One coalesced 1KB load per B-fragment.
__device__ __forceinline__ int packidx(int col, int k, int Kd) {
  int lane = ((k & 31) >> 3) * 16 + (col & 15);
  int c = (((col >> 6) * (Kd >> 5) + (k >> 5)) * 4 + ((col >> 4) & 3)) * 64 + lane;
  return c * 8 + (k & 7);
}

// ---------------- CSR build (no global atomics, no rnk array) ----------------
// Counts/offsets fit ushort: per-chunk per-bin count <= CHSZ; exclusive offset
// <= deg(bin) (~16 mean, max ~70 for this fixed Poisson input).
__global__ __launch_bounds__(256) void histp_k(const int* __restrict__ dst,
                                               ushort_t* __restrict__ partial) {
  __shared__ uint32 lh[RGSZ];
  const int c = blockIdx.x & (NCH - 1);
  const int rg = blockIdx.x >> 6;
  const int r0 = rg * RGSZ;
  for (int i = threadIdx.x; i < RGSZ; i += 256) lh[i] = 0;
  __syncthreads();
  const int e0 = c * CHSZ;
  for (int i = threadIdx.x; i < CHSZ; i += 256) {
    int d = dst[e0 + i] - r0;
    if ((unsigned)d < (unsigned)RGSZ) atomicAdd(&lh[d], 1u);
  }
  __syncthreads();
  ushort_t* po = partial + (size_t)c * NN + r0;
  for (int i = threadIdx.x; i < RGSZ; i += 256) po[i] = (ushort_t)lh[i];
}

// Per-bin exclusive scan across the 64 chunk-partials (in place) -> cnt,
// with the per-1024-bin block sum (bsum) fused in (replaces bsum_k).
// 49 blocks x 1024 threads matches scan2_k's partitioning exactly.
__global__ __launch_bounds__(1024) void coffb_k(ushort_t* __restrict__ partial,
                                                int* __restrict__ cnt,
                                                int* __restrict__ bsum) {
  __shared__ int ws[16];
  const int tid = threadIdx.x, ln = tid & 63, wv = tid >> 6;
  const int bin = blockIdx.x * 1024 + tid;
  int run = 0;
  if (bin < NN) {
#pragma unroll
    for (int c = 0; c < NCH; c++) {
      int t = partial[(size_t)c * NN + bin];
      partial[(size_t)c * NN + bin] = (ushort_t)run;
      run += t;
    }
    cnt[bin] = run;
  }
  int v = (bin < NN) ? run : 0;
#pragma unroll
  for (int d = 32; d; d >>= 1) v += __shfl_down(v, d, 64);
  if (ln == 0) ws[wv] = v;
  __syncthreads();
  if (tid < 16) {
    int s = ws[tid];
#pragma unroll
    for (int d = 8; d; d >>= 1) s += __shfl_down(s, d, 64);
    if (tid == 0) bsum[blockIdx.x] = s;
  }
}

__global__ void bscan_k(int* __restrict__ bsum, int* __restrict__ rp) {
  int tid = threadIdx.x;
  int v = (tid < NBLK) ? bsum[tid] : 0;
  int x = v;
#pragma unroll
  for (int d = 1; d < 64; d <<= 1) {
    int t = __shfl_up(x, d, 64);
    if (tid >= d) x += t;
  }
  if (tid < NBLK) bsum[tid] = x - v;
  if (tid == 0) rp[NN] = NE;
}

__global__ void scan2_k(const int* __restrict__ cnt, const int* __restrict__ bsum,
                        int* __restrict__ rp) {
  __shared__ int ws[16];
  const int tid = threadIdx.x, ln = tid & 63, wv = tid >> 6;
  int i = blockIdx.x * 1024 + tid;
  int v = (i < NN) ? cnt[i] : 0;
  int x = v;
#pragma unroll
  for (int d = 1; d < 64; d <<= 1) {
    int t = __shfl_up(x, d, 64);
    if (ln >= d) x += t;
  }
  if (ln == 63) ws[wv] = x;
  __syncthreads();
  if (tid < 16) {
    int s = ws[tid];
#pragma unroll
    for (int d = 1; d < 16; d <<= 1) {
      int t = __shfl_up(s, d, 64);
      if (tid >= d) s += t;
    }
    ws[tid] = s;
  }
  __syncthreads();
  int excl = x - v + (wv ? ws[wv - 1] : 0) + bsum[blockIdx.x];
  if (i < NN) rp[i] = excl;
}

__global__ __launch_bounds__(256) void scat3_k(const int* __restrict__ src,
                                               const int* __restrict__ dst,
                                               const int* __restrict__ rp,
                                               const ushort_t* __restrict__ partial,
                                               int* __restrict__ esrc) {
  __shared__ int base[RGSZ];     // 25 KB
  __shared__ uint32 lh[RGSZ];    // 25 KB
  const int c = blockIdx.x & (NCH - 1);
  const int rg = blockIdx.x >> 6;
  const int r0 = rg * RGSZ;
  const ushort_t* po = partial + (size_t)c * NN + r0;
  const int* rpo = rp + r0;
  for (int i = threadIdx.x; i < RGSZ; i += 256) {
    base[i] = rpo[i] + (int)po[i];
    lh[i] = 0;
  }
  __syncthreads();
  const int e0 = c * CHSZ;
  for (int i = threadIdx.x; i < CHSZ; i += 256) {
    int e = e0 + i;
    int d = dst[e] - r0;
    if ((unsigned)d < (unsigned)RGSZ) {
      int r = (int)atomicAdd(&lh[d], 1u);
      esrc[base[d] + r] = src[e];
    }
  }
}

// ---------------- prep: weights (6 transposes -> frag-pack) + BN folding ----------------
__global__ void prep_k(const float* __restrict__ w1_0, const float* __restrict__ w2_0,
                       const float* __restrict__ w1_r, const float* __restrict__ w2_r,
                       const float* b1_0, const float* b2_0, const float* g0,
                       const float* be0, const float* m0, const float* v0,
                       const float* b1_r, const float* b2_r, const float* g_r,
                       const float* be_r, const float* m_r, const float* v_r,
                       ushort_t* __restrict__ wt,
                       float* bi1, float* sc2, float* bi2) {
  const int which = blockIdx.y;
  if (which < 6) {
    const int n = blockIdx.x, k = threadIdx.x;
    const float* w; ushort_t* o; int K = HID;
    switch (which) {
      case 0: w = w1_0; o = wt; K = IND; break;
      case 1: w = w2_0; o = wt + HID * IND; break;
      case 2: w = w1_r; o = wt + HID * IND + 1 * HID * HID; break;
      case 3: w = w2_r; o = wt + HID * IND + 2 * HID * HID; break;
      case 4: w = w1_r + HID * HID; o = wt + HID * IND + 3 * HID * HID; break;
      default: w = w2_r + HID * HID; o = wt + HID * IND + 4 * HID * HID; break;
    }
    if (k < K) o[packidx(n, k, K)] = f2b(w[(size_t)k * HID + n]);
  } else {
    const int l = blockIdx.x;
    if (l >= 3) return;
    const int j = threadIdx.x;
    float b1, b2, g, be, m, v;
    if (l == 0) { b1 = b1_0[j]; b2 = b2_0[j]; g = g0[j]; be = be0[j]; m = m0[j]; v = v0[j]; }
    else { int o = (l - 1) * HID + j; b1 = b1_r[o]; b2 = b2_r[o]; g = g_r[o]; be = be_r[o]; m = m_r[o]; v = v_r[o]; }
    int o = l * HID + j;
    bi1[o] = b1;
    float s = g * rsqrtf(v + 1e-5f);
    sc2[o] = s;
    bi2[o] = (b2 - m) * s + be;
  }
}

// cast x (NN x 128 fp32) -> bf16
__global__ void x2b_k(const float* __restrict__ x, ushort_t* __restrict__ xb) {
  int i = blockIdx.x * 256 + threadIdx.x;
  const int n = NN * IND / 2;
  if (i < n) {
    float2 f = ((const float2*)x)[i];
    ((uint32*)xb)[i] = pack2(f.x, f.y);
  }
}

// ---------------- aggregation: z = h + sum h_j ----------------
// R10-proven: 8-deep gather batches + idx prefetch pipeline + branch-free
// padded-8 tail (clamped dup idx, 0/1 fma weights). R11's 16-deep variant
// regressed (VGPR 44 -> occupancy 40%); 8-deep is the measured sweet spot.
__global__ void agg256_k(const ushort_t* __restrict__ h, const int* __restrict__ rp,
                         const int* __restrict__ esrc, ushort_t* __restrict__ z) {
  int wid = threadIdx.x >> 6, lane = threadIdx.x & 63;
  int node = blockIdx.x * 4 + wid;
  if (node >= NN) return;
  const uint2* hp = (const uint2*)h;
  uint2 v = hp[(size_t)node * 64 + lane];
  float a0 = blo(v.x), a1 = bhi(v.x), a2 = blo(v.y), a3 = bhi(v.y);
  int e0 = rp[node], e1 = rp[node + 1];
  const int nfull = (e1 - e0) >> 3;
  int s[8], sn[8];
  if (nfull > 0) {
#pragma unroll
    for (int q = 0; q < 8; q++) s[q] = esrc[e0 + q];
  }
  for (int b = 0; b < nfull; b++) {
    const int e = e0 + b * 8;
    if (b + 1 < nfull) {
#pragma unroll
      for (int q = 0; q < 8; q++) sn[q] = esrc[e + 8 + q];
    }
    uint2 u[8];
#pragma unroll
    for (int q = 0; q < 8; q++) u[q] = hp[(size_t)s[q] * 64 + lane];
#pragma unroll
    for (int q = 0; q < 8; q++) {
      a0 += blo(u[q].x); a1 += bhi(u[q].x); a2 += blo(u[q].y); a3 += bhi(u[q].y);
    }
#pragma unroll
    for (int q = 0; q < 8; q++) s[q] = sn[q];
  }
  const int e = e0 + nfull * 8;
  if (e < e1) {
    const int last = e1 - 1;
    int idx[8]; float w[8];
#pragma unroll
    for (int q = 0; q < 8; q++) {
      int ee = e + q;
      w[q] = (ee < e1) ? 1.f : 0.f;
      idx[q] = esrc[(ee < e1) ? ee : last];
    }
    uint2 u[8];
#pragma unroll
    for (int q = 0; q < 8; q++) u[q] = hp[(size_t)idx[q] * 64 + lane];
#pragma unroll
    for (int q = 0; q < 8; q++) {
      a0 = fmaf(w[q], blo(u[q].x), a0);
      a1 = fmaf(w[q], bhi(u[q].x), a1);
      a2 = fmaf(w[q], blo(u[q].y), a2);
      a3 = fmaf(w[q], bhi(u[q].y), a3);
    }
  }
  uint2 o; o.x = pack2(a0, a1); o.y = pack2(a2, a3);
  ((uint2*)z)[(size_t)node * 64 + lane] = o;
}

__global__ void agg128_k(const ushort_t* __restrict__ h, const int* __restrict__ rp,
                         const int* __restrict__ esrc, ushort_t* __restrict__ z) {
  int wid = threadIdx.x >> 6, lane = threadIdx.x & 63;
  int node = blockIdx.x * 4 + wid;
  if (node >= NN) return;
  const uint32* hp = (const uint32*)h;
  uint32 v = hp[(size_t)node * 64 + lane];
  float a0 = blo(v), a1 = bhi(v);
  int e0 = rp[node], e1 = rp[node + 1];
  const int nfull = (e1 - e0) >> 3;
  int s[8], sn[8];
  if (nfull > 0) {
#pragma unroll
    for (int q = 0; q < 8; q++) s[q] = esrc[e0 + q];
  }
  for (int b = 0; b < nfull; b++) {
    const int e = e0 + b * 8;
    if (b + 1 < nfull) {
#pragma unroll
      for (int q = 0; q < 8; q++) sn[q] = esrc[e + 8 + q];
    }
    uint32 u[8];
#pragma unroll
    for (int q = 0; q < 8; q++) u[q] = hp[(size_t)s[q] * 64 + lane];
#pragma unroll
    for (int q = 0; q < 8; q++) { a0 += blo(u[q]); a1 += bhi(u[q]); }
#pragma unroll
    for (int q = 0; q < 8; q++) s[q] = sn[q];
  }
  const int e = e0 + nfull * 8;
  if (e < e1) {
    const int last = e1 - 1;
    int idx[8]; float w[8];
#pragma unroll
    for (int q = 0; q < 8; q++) {
      int ee = e + q;
      w[q] = (ee < e1) ? 1.f : 0.f;
      idx[q] = esrc[(ee < e1) ? ee : last];
    }
    uint32 u[8];
#pragma unroll
    for (int q = 0; q < 8; q++) u[q] = hp[(size_t)idx[q] * 64 + lane];
#pragma unroll
    for (int q = 0; q < 8; q++) {
      a0 = fmaf(w[q], blo(u[q]), a0);
      a1 = fmaf(w[q], bhi(u[q]), a1);
    }
  }
  ((uint32*)z)[(size_t)node * 64 + lane] = pack2(a0, a1);
}

// ---------------- fused MLP: out = BN(lrelu(Z W1 + b1) W2 + b2) [opt lrelu] -----------
// R9-proven GEMM structure (A-tile LDS-staged, source-swizzled; B global
// frag-packed; 4 blocks/CU) + R13 coalesced epilogue (repack via S, stream
// out row-major: bf16 8B/lane, f32 16B/lane in two halves).
template<int K1>
__global__ __launch_bounds__(256, 4) void fgemm_k(
    const ushort_t* __restrict__ A, const ushort_t* __restrict__ B1t,
    const ushort_t* __restrict__ B2t, const float* __restrict__ bi1,
    const float* __restrict__ sc2, const float* __restrict__ bi2,
    void* __restrict__ out, int lrelu2, int f32out) {
  __shared__ __attribute__((aligned(16))) ushort_t S[64 * 264];  // 33 KB
  const int tid = threadIdx.x;
  const int lane = tid & 63;
  const int wid = tid >> 6;
  const int m0 = blockIdx.x * 64;
  const int fr = lane & 15;
  const int fk = (lane >> 4) * 8;
  const int er = lane >> 4;
  const int ec = lane & 15;
  constexpr int S1 = K1 / 32;          // K-steps: 4 or 8
  constexpr int CH = K1 / 8;           // 16B chunks per row: 16 or 32
  constexpr int NL = (64 * CH) / 256;  // gload_lds per thread: 4 or 8

  const short8* Bp1 = (const short8*)B1t;   // frag-packed: chunk ((wid*S1+ks)*4+j)*64+lane
  const short8* Bp2 = (const short8*)B2t;

  // ---- phase 0: bulk-stage A-tile (64 x K1) into LDS, source-swizzled ----
#pragma unroll
  for (int l = 0; l < NL; l++) {
    int off16 = l * 256 + tid;          // 16B-chunk index in linear LDS
    int row = off16 / CH;
    int sch = off16 & (CH - 1);
    int lch = sch ^ (row & (CH - 1));   // involution: slot sch holds logical chunk lch
    __builtin_amdgcn_global_load_lds((gptr_t)(A + (size_t)(m0 + row) * K1 + lch * 8),
                                     (lptr_t)(S + (size_t)off16 * 8), 16, 0, 0);
  }

  f32x4 zero = {0.f, 0.f, 0.f, 0.f};
  f32x4 acc[4][4];
#pragma unroll
  for (int i = 0; i < 4; i++)
#pragma unroll
    for (int j = 0; j < 4; j++) acc[i][j] = zero;

  __syncthreads();   // barrier 1: A staged (implicit vmcnt drain)

  // ---- phase 1: Z (64 x K1, LDS) * W1 (K1 x 256, global frag-pack) ----
#pragma unroll 2
  for (int ks = 0; ks < S1; ks++) {
    short8 af[4], bfv[4];
#pragma unroll
    for (int i = 0; i < 4; i++) {
      int row = i * 16 + fr;
      int lc = ks * 4 + (lane >> 4);
      int sch = lc ^ (row & (CH - 1));
      af[i] = *(const short8*)(S + row * K1 + sch * 8);
    }
#pragma unroll
    for (int j = 0; j < 4; j++)
      bfv[j] = Bp1[((wid * S1 + ks) * 4 + j) * 64 + lane];
#pragma unroll
    for (int i = 0; i < 4; i++)
#pragma unroll
      for (int j = 0; j < 4; j++)
        acc[i][j] = __builtin_amdgcn_mfma_f32_16x16x32_bf16(af[i], bfv[j], acc[i][j], 0, 0, 0);
  }

  __syncthreads();   // barrier 2: all waves done reading A before C1 overwrites S

  // C1 = lrelu(acc + b1) -> S (stride 264)
#pragma unroll
  for (int j = 0; j < 4; j++) {
    int col = wid * 64 + j * 16 + ec;
    float b = bi1[col];
#pragma unroll
    for (int i = 0; i < 4; i++) {
#pragma unroll
      for (int r = 0; r < 4; r++) {
        int row = i * 16 + er * 4 + r;
        float v = acc[i][j][r] + b;
        v = (v > 0.f) ? v : 0.01f * v;
        S[row * 264 + col] = f2b(v);
      }
    }
  }
  __syncthreads();   // barrier 3: publish C1

  // ---- phase 2: C1 (64 x 256, LDS) * W2 (256 x 256, global frag-pack) ----
  f32x4 acc2[4][4];
#pragma unroll
  for (int i = 0; i < 4; i++)
#pragma unroll
    for (int j = 0; j < 4; j++) acc2[i][j] = zero;

#pragma unroll 2
  for (int ks = 0; ks < 8; ks++) {
    const int kk = ks * 32;
    short8 af[4], bfv[4];
#pragma unroll
    for (int i = 0; i < 4; i++)
      af[i] = *(const short8*)(S + (i * 16 + fr) * 264 + kk + fk);
#pragma unroll
    for (int j = 0; j < 4; j++)
      bfv[j] = Bp2[((wid * 8 + ks) * 4 + j) * 64 + lane];
#pragma unroll
    for (int i = 0; i < 4; i++)
#pragma unroll
      for (int j = 0; j < 4; j++)
        acc2[i][j] = __builtin_amdgcn_mfma_f32_16x16x32_bf16(af[i], bfv[j], acc2[i][j], 0, 0, 0);
  }

  __syncthreads();   // barrier 4: C1 reads done; S reusable for the repack

  // ---- epilogue: BN fold (+opt lrelu), repack via S, coalesced store ----
  if (!f32out) {
#pragma unroll
    for (int j = 0; j < 4; j++) {
      int col = wid * 64 + j * 16 + ec;
      float s = sc2[col], b = bi2[col];
#pragma unroll
      for (int i = 0; i < 4; i++) {
#pragma unroll
        for (int r = 0; r < 4; r++) {
          int row = i * 16 + er * 4 + r;
          float v = acc2[i][j][r] * s + b;
          if (lrelu2) v = (v > 0.f) ? v : 0.01f * v;
          S[row * 264 + col] = f2b(v);
        }
      }
    }
    __syncthreads();
    // wave wid -> rows wid*16..+15; lane stores 8B (4 ushorts), 512B/row segment
#pragma unroll
    for (int rr = 0; rr < 16; rr++) {
      int row = wid * 16 + rr;
      int grow = m0 + row;
      if (grow < NN) {
        uint2 val;
        val.x = *(const uint32*)(S + row * 264 + lane * 4);
        val.y = *(const uint32*)(S + row * 264 + lane * 4 + 2);
        *(uint2*)((ushort_t*)out + (size_t)grow * HID + lane * 4) = val;
      }
    }
  } else {
    float* Sf = (float*)S;   // [32][264] f32 per half
#pragma unroll
    for (int half = 0; half < 2; half++) {
#pragma unroll
      for (int j = 0; j < 4; j++) {
        int col = wid * 64 + j * 16 + ec;
        float s = sc2[col], b = bi2[col];
#pragma unroll
        for (int i2 = 0; i2 < 2; i2++) {
          int i = half * 2 + i2;
#pragma unroll
          for (int r = 0; r < 4; r++) {
            int row = i2 * 16 + er * 4 + r;   // 0..31 within half
            float v = acc2[i][j][r] * s + b;
            if (lrelu2) v = (v > 0.f) ? v : 0.01f * v;
            Sf[row * 264 + col] = v;
          }
        }
      }
      __syncthreads();
      // wave wid -> 8 rows; lane stores 16B f32x4, 1KB/row segment
#pragma unroll
      for (int rr = 0; rr < 8; rr++) {
        int row = wid * 8 + rr;              // 0..31
        int grow = m0 + half * 32 + row;
        if (grow < NN) {
          f32x4 val = *(const f32x4*)(Sf + row * 264 + lane * 4);
          *(f32x4*)((float*)out + (size_t)grow * HID + lane * 4) = val;
        }
      }
      if (half == 0) __syncthreads();   // drain reads before half-1 overwrites Sf
    }
  }
}

extern "C" void kernel_launch(void* const* d_in, const int* in_sizes, int n_in,
                              void* d_out, int out_size, void* d_ws, size_t ws_size,
                              hipStream_t stream) {
  const float* x    = (const float*)d_in[0];
  const int*   src  = (const int*)d_in[1];
  const int*   dst  = (const int*)d_in[2];
  const float* w1_0 = (const float*)d_in[3];
  const float* b1_0 = (const float*)d_in[4];
  const float* w2_0 = (const float*)d_in[5];
  const float* b2_0 = (const float*)d_in[6];
  const float* g0   = (const float*)d_in[7];
  const float* be0  = (const float*)d_in[8];
  const float* m0   = (const float*)d_in[9];
  const float* v0   = (const float*)d_in[10];
  const float* w1_r = (const float*)d_in[11];
  const float* b1_r = (const float*)d_in[12];
  const float* w2_r = (const float*)d_in[13];
  const float* b2_r = (const float*)d_in[14];
  const float* g_r  = (const float*)d_in[15];
  const float* be_r = (const float*)d_in[16];
  const float* m_r  = (const float*)d_in[17];
  const float* v_r  = (const float*)d_in[18];

  char* ws = (char*)d_ws;
  size_t off = 0;
  auto alloc = [&](size_t bytes) {
    void* p = ws + off;
    off = (off + bytes + 255) & ~(size_t)255;
    return p;
  };
  ushort_t* bufA  = (ushort_t*)alloc((size_t)MPAD * HID * 2);
  ushort_t* bufB  = (ushort_t*)alloc((size_t)MPAD * HID * 2);
  ushort_t* xb    = (ushort_t*)alloc((size_t)MPAD * IND * 2);
  int*      rp    = (int*)alloc((NN + 1) * sizeof(int));
  int*      cnt   = (int*)alloc(NN * sizeof(int));
  int*      bsum  = (int*)alloc(NBLK * sizeof(int));
  int*      esrc  = (int*)alloc((size_t)NE * sizeof(int));
  ushort_t* wt    = (ushort_t*)alloc(((size_t)HID * IND + 5 * (size_t)HID * HID) * 2);
  float*    bi1   = (float*)alloc(3 * HID * sizeof(float));
  float*    sc2   = (float*)alloc(3 * HID * sizeof(float));
  float*    bi2   = (float*)alloc(3 * HID * sizeof(float));
  (void)ws_size; (void)in_sizes; (void)n_in; (void)out_size;

  // CSR scratch aliases compute buffers (used strictly before agg/fgemm write them)
  ushort_t* partial = (ushort_t*)bufA;   // 64 * 50000 * 2B = 6.4 MB <= 25.6 MB

  ushort_t* w1_0t = wt;
  ushort_t* w2_0t = wt + HID * IND;
  ushort_t* w1r0t = wt + HID * IND + 1 * HID * HID;
  ushort_t* w2r0t = wt + HID * IND + 2 * HID * HID;
  ushort_t* w1r1t = wt + HID * IND + 3 * HID * HID;
  ushort_t* w2r1t = wt + HID * IND + 4 * HID * HID;

  // CSR build (atomic-free, ushort partials, rank recomputed in scatter)
  histp_k<<<NCH * NRG, 256, 0, stream>>>(dst, partial);
  coffb_k<<<NBLK, 1024, 0, stream>>>(partial, cnt, bsum);
  bscan_k<<<1, 64, 0, stream>>>(bsum, rp);
  scan2_k<<<NBLK, 1024, 0, stream>>>(cnt, bsum, rp);
  scat3_k<<<NCH * NRG, 256, 0, stream>>>(src, dst, rp, partial, esrc);

  // weight/BN/input prep
  prep_k<<<dim3(HID, 7), 256, 0, stream>>>(w1_0, w2_0, w1_r, w2_r,
                                           b1_0, b2_0, g0, be0, m0, v0,
                                           b1_r, b2_r, g_r, be_r, m_r, v_r,
                                           wt, bi1, sc2, bi2);
  x2b_k<<<(NN * IND / 2 + 255) / 256, 256, 0, stream>>>(x, xb);

  const int GG = MPAD / 64;  // 782
  // layer 0
  agg128_k<<<NN / 4, 256, 0, stream>>>(xb, rp, esrc, bufA);
  fgemm_k<IND><<<GG, 256, 0, stream>>>(bufA, w1_0t, w2_0t, bi1, sc2, bi2, bufB, 1, 0);
  // layer 1
  agg256_k<<<NN / 4, 256, 0, stream>>>(bufB, rp, esrc, bufA);
  fgemm_k<HID><<<GG, 256, 0, stream>>>(bufA, w1r0t, w2r0t, bi1 + HID, sc2 + HID, bi2 + HID, bufB, 1, 0);
  // layer 2
  agg256_k<<<NN / 4, 256, 0, stream>>>(bufB, rp, esrc, bufA);
  fgemm_k<HID><<<GG, 256, 0, stream>>>(bufA, w1r1t, w2r1t, bi1 + 2 * HID, sc2 + 2 * HID, bi2 + 2 * HID, d_out, 0, 1);
}